// Round 2
// 2168.042 us; speedup vs baseline: 1.3184x; 1.3184x over previous
//
#include <hip/hip_runtime.h>
#include <cstddef>

// Qwen3.5 MTP layer, MI355X gfx950. Round 3: MFMA flash attention, no inline asm.
// T=2048 H=2048 V=32000 NH=16 NKV=4 DH=128 E=16 K=2 I=1024
// Pre-router GEMMs + attention: split-bf16 (hi+lo) on BOTH operands -> ~2^-17 rel
// error. Post-router MoE: single bf16 (unchanged).
// V projection GEMM writes V^T (MODE 3) so flash PV B-fragments are contiguous
// ds_read_b128 (no hardware transpose reads needed).

typedef unsigned short u16b;
typedef __attribute__((ext_vector_type(8))) short s8v;   // 8 x bf16 frag
typedef __attribute__((ext_vector_type(4))) float f4v;   // MFMA acc

#define T_TOK 2048
#define HID   2048

__device__ __forceinline__ float bf2f(u16b h) {
  return __uint_as_float(((unsigned int)h) << 16);
}
__device__ __forceinline__ u16b f2bf(float f) {
  unsigned int u = __float_as_uint(f);
  return (u16b)((u + 0x7fffu + ((u >> 16) & 1u)) >> 16);
}
__device__ __forceinline__ void split2(float f, u16b& hi, u16b& lo) {
  hi = f2bf(f);
  lo = f2bf(f - bf2f(hi));
}
__device__ __forceinline__ unsigned long long pack4(const u16b* p) {
  return (unsigned long long)p[0] | ((unsigned long long)p[1] << 16) |
         ((unsigned long long)p[2] << 32) | ((unsigned long long)p[3] << 48);
}
__device__ __forceinline__ f4v mfma_b(s8v a, s8v b, f4v c) {
  return __builtin_amdgcn_mfma_f32_16x16x32_bf16(a, b, c, 0, 0, 0);
}
union FragCvt { unsigned long long q[2]; s8v v; };

// block=256 sum-reduce
__device__ __forceinline__ float blk_sum_256(float v, float* lds4) {
  #pragma unroll
  for (int off = 32; off > 0; off >>= 1) v += __shfl_down(v, off);
  int tid = threadIdx.x;
  if ((tid & 63) == 0) lds4[tid >> 6] = v;
  __syncthreads();
  return lds4[0] + lds4[1] + lds4[2] + lds4[3];
}

// ---------------- zero counts ----------------
__global__ void zero_counts_kernel(int* counts) {
  if (threadIdx.x < 16) counts[threadIdx.x] = 0;
}

// ---------------- embed gather + RMS + concat ----------------
__global__ __launch_bounds__(256) void embed_cat_kernel(
    const int* __restrict__ ids, const float* __restrict__ embw,
    const float* __restrict__ hid, const float* __restrict__ w_emb,
    const float* __restrict__ w_hid, float* __restrict__ cat) {
  __shared__ float lds[4];
  int t = blockIdx.x, which = blockIdx.y, tid = threadIdx.x;
  const float* src;
  const float* w;
  float* dst;
  if (which == 0) { src = embw + (size_t)ids[t] * HID; w = w_emb; dst = cat + (size_t)t * 4096; }
  else            { src = hid  + (size_t)t * HID;      w = w_hid; dst = cat + (size_t)t * 4096 + HID; }
  float v[8]; float ss = 0.f;
  #pragma unroll
  for (int i = 0; i < 8; ++i) { v[i] = src[tid + i * 256]; ss += v[i] * v[i]; }
  float tot = blk_sum_256(ss, lds);
  float scale = rsqrtf(tot * (1.f / (float)HID) + 1e-6f);
  #pragma unroll
  for (int i = 0; i < 8; ++i) {
    int j = tid + i * 256;
    dst[j] = v[i] * scale * (1.f + w[j]);
  }
}

// ---------------- RMS norm on f32 rows ----------------
__global__ __launch_bounds__(256) void rms_f32_kernel(
    const float* __restrict__ X, const float* __restrict__ W, float* __restrict__ Y) {
  __shared__ float lds[4];
  int t = blockIdx.x, tid = threadIdx.x;
  const float* row = X + (size_t)t * HID;
  float v[8]; float ss = 0.f;
  #pragma unroll
  for (int i = 0; i < 8; ++i) { v[i] = row[tid + i * 256]; ss += v[i] * v[i]; }
  float tot = blk_sum_256(ss, lds);
  float scale = rsqrtf(tot * (1.f / (float)HID) + 1e-6f);
  float* yrow = Y + (size_t)t * HID;
  #pragma unroll
  for (int i = 0; i < 8; ++i) {
    int j = tid + i * 256;
    yrow[j] = v[i] * scale * (1.f + W[j]);
  }
}

// ---------------- per-head RMS + RoPE (in place) ----------------
__global__ __launch_bounds__(128) void qknorm_rope_kernel(
    float* __restrict__ X, const float* __restrict__ W,
    const int* __restrict__ positions, int ld) {
  __shared__ float wsum[2];
  __shared__ float xs[128];
  __shared__ float sc;
  int t = blockIdx.x, hh = blockIdx.y, d = threadIdx.x;
  float* row = X + (size_t)t * ld + hh * 128;
  float x = row[d];
  float ss = x * x;
  #pragma unroll
  for (int off = 32; off > 0; off >>= 1) ss += __shfl_down(ss, off);
  if ((d & 63) == 0) wsum[d >> 6] = ss;
  __syncthreads();
  if (d == 0) sc = rsqrtf((wsum[0] + wsum[1]) * (1.f / 128.f) + 1e-6f);
  __syncthreads();
  float xn = x * sc * (1.f + W[d]);
  xs[d] = xn;
  __syncthreads();
  int pos = positions[t];
  int i = d & 63;
  // 1/theta^(i/64) = 2^(-i*log2(1e6)/64)
  float invf = exp2f((float)i * (-19.931568569324174f / 64.f));
  float ang = (float)pos * invf;
  float cv = cosf(ang), sv = sinf(ang);
  float other = xs[d ^ 64];
  row[d] = (d < 64) ? (xn * cv - other * sv) : (xn * cv + other * sv);
}

// ---------------- MFMA GEMM (A,B both f32 in memory) ----------------
// MODE 0: C[M,N] = A*B [+ addend]; split-bf16 hi/lo on BOTH A and B (3 MFMAs)
// MODE 3: same compute as MODE 0, but C written TRANSPOSED: Ct[N,M] (no addend)
// MODE 1: gathered gate/up (hi only): C h[slot] = silu(g)*u
// MODE 2: gathered down (hi only): C moeout[slot] = acc*gate[slot]
template <int MODE>
__global__ __launch_bounds__(256) void gemm_k(
    const float* __restrict__ A, const float* __restrict__ B,
    const float* __restrict__ B2, float* __restrict__ C,
    const float* __restrict__ addend, const int* __restrict__ counts,
    const int* __restrict__ list, const float* __restrict__ gatebuf,
    int M, int N, int K) {
  constexpr bool FULL = (MODE == 0 || MODE == 3);
  __shared__ u16b As[64 * 40];
  __shared__ u16b Al[64 * 40];
  __shared__ u16b Bs[64 * 40];
  __shared__ u16b Bl[64 * 40];
  __shared__ u16b B2s[64 * 40];

  int n0 = blockIdx.x * 64;
  int m0 = blockIdx.y * 64;
  int cnt = M;
  if (MODE == 1 || MODE == 2) {
    int e = blockIdx.z;
    cnt = counts[e];
    if (m0 >= cnt) return;
    list += e * T_TOK;
    B += (size_t)e * K * N;
    if (MODE == 1) B2 += (size_t)e * K * N;
  }

  int tid = threadIdx.x;
  int wave = tid >> 6, lane = tid & 63;
  int wm = wave >> 1, wn = wave & 1;
  int l16 = lane & 15, quad = lane >> 4;

  int am = tid >> 2, ak = (tid & 3) * 8;      // A stage: 64 rows x 32 k
  int bk = tid >> 3, bn = (tid & 7) * 8;      // B stage: 32 k x 64 n

  const float* aptr;
  if (FULL) {
    aptr = A + (size_t)(m0 + am) * K + ak;
  } else {
    int mr = m0 + am;
    if (mr > cnt - 1) mr = cnt - 1;
    int entry = list[mr];
    int arow = (MODE == 1) ? (entry >> 1) : entry;
    aptr = A + (size_t)arow * K + ak;
  }
  const float* bptr = B + (size_t)bk * N + n0 + bn;
  const float* b2ptr = nullptr;
  if (MODE == 1) b2ptr = B2 + (size_t)bk * N + n0 + bn;

  f4v acc[2][2];
  f4v acc2[2][2];
  #pragma unroll
  for (int i = 0; i < 2; ++i)
    #pragma unroll
    for (int j = 0; j < 2; ++j) { acc[i][j] = (f4v)0.0f; acc2[i][j] = (f4v)0.0f; }

  for (int k0 = 0; k0 < K; k0 += 32) {
    __syncthreads();
    // ---- stage A (f32 -> bf16 hi [+lo]) ----
    {
      const float* ap = aptr + k0;
      float4 f0 = *(const float4*)ap;
      float4 f1 = *(const float4*)(ap + 4);
      float f[8] = {f0.x, f0.y, f0.z, f0.w, f1.x, f1.y, f1.z, f1.w};
      u16b hi[8], lo[8];
      #pragma unroll
      for (int x = 0; x < 8; ++x) {
        split2(f[x], hi[x], lo[x]);
      }
      *(unsigned long long*)&As[am * 40 + ak]     = pack4(hi);
      *(unsigned long long*)&As[am * 40 + ak + 4] = pack4(hi + 4);
      if (FULL) {
        *(unsigned long long*)&Al[am * 40 + ak]     = pack4(lo);
        *(unsigned long long*)&Al[am * 40 + ak + 4] = pack4(lo + 4);
      }
    }
    // ---- stage B transposed: Bs[n][k], f32 -> bf16 hi [+lo] ----
    {
      const float* bp = bptr + (size_t)k0 * N;
      float4 g0 = *(const float4*)bp;
      float4 g1 = *(const float4*)(bp + 4);
      float f[8] = {g0.x, g0.y, g0.z, g0.w, g1.x, g1.y, g1.z, g1.w};
      #pragma unroll
      for (int x = 0; x < 8; ++x) {
        u16b h, l;
        split2(f[x], h, l);
        Bs[(bn + x) * 40 + bk] = h;
        if (FULL) Bl[(bn + x) * 40 + bk] = l;
      }
      if (MODE == 1) {
        const float* cp = b2ptr + (size_t)k0 * N;
        float4 h0 = *(const float4*)cp;
        float4 h1 = *(const float4*)(cp + 4);
        float f2[8] = {h0.x, h0.y, h0.z, h0.w, h1.x, h1.y, h1.z, h1.w};
        #pragma unroll
        for (int x = 0; x < 8; ++x) B2s[(bn + x) * 40 + bk] = f2bf(f2[x]);
      }
    }
    __syncthreads();
    // ---- MFMA: 2x2 16x16 subtiles per wave ----
    s8v a0 = *(const s8v*)&As[(wm * 32 + l16) * 40 + quad * 8];
    s8v a1 = *(const s8v*)&As[(wm * 32 + 16 + l16) * 40 + quad * 8];
    s8v b0 = *(const s8v*)&Bs[(wn * 32 + l16) * 40 + quad * 8];
    s8v b1 = *(const s8v*)&Bs[(wn * 32 + 16 + l16) * 40 + quad * 8];
    acc[0][0] = mfma_b(a0, b0, acc[0][0]);
    acc[0][1] = mfma_b(a0, b1, acc[0][1]);
    acc[1][0] = mfma_b(a1, b0, acc[1][0]);
    acc[1][1] = mfma_b(a1, b1, acc[1][1]);
    if (FULL) {
      s8v a0l = *(const s8v*)&Al[(wm * 32 + l16) * 40 + quad * 8];
      s8v a1l = *(const s8v*)&Al[(wm * 32 + 16 + l16) * 40 + quad * 8];
      s8v b0l = *(const s8v*)&Bl[(wn * 32 + l16) * 40 + quad * 8];
      s8v b1l = *(const s8v*)&Bl[(wn * 32 + 16 + l16) * 40 + quad * 8];
      // a*bl
      acc[0][0] = mfma_b(a0, b0l, acc[0][0]);
      acc[0][1] = mfma_b(a0, b1l, acc[0][1]);
      acc[1][0] = mfma_b(a1, b0l, acc[1][0]);
      acc[1][1] = mfma_b(a1, b1l, acc[1][1]);
      // al*b
      acc[0][0] = mfma_b(a0l, b0, acc[0][0]);
      acc[0][1] = mfma_b(a0l, b1, acc[0][1]);
      acc[1][0] = mfma_b(a1l, b0, acc[1][0]);
      acc[1][1] = mfma_b(a1l, b1, acc[1][1]);
    }
    if (MODE == 1) {
      s8v c0 = *(const s8v*)&B2s[(wn * 32 + l16) * 40 + quad * 8];
      s8v c1 = *(const s8v*)&B2s[(wn * 32 + 16 + l16) * 40 + quad * 8];
      acc2[0][0] = mfma_b(a0, c0, acc2[0][0]);
      acc2[0][1] = mfma_b(a0, c1, acc2[0][1]);
      acc2[1][0] = mfma_b(a1, c0, acc2[1][0]);
      acc2[1][1] = mfma_b(a1, c1, acc2[1][1]);
    }
  }

  // ---- epilogue ----
  if (MODE == 3) {
    // transposed write: Ct[col][mrow], per-lane float4 along M
    #pragma unroll
    for (int i = 0; i < 2; ++i)
      #pragma unroll
      for (int j = 0; j < 2; ++j) {
        int col = n0 + wn * 32 + j * 16 + l16;
        int mbase = m0 + wm * 32 + i * 16 + quad * 4;
        float4 vv;
        vv.x = acc[i][j][0]; vv.y = acc[i][j][1];
        vv.z = acc[i][j][2]; vv.w = acc[i][j][3];
        *(float4*)&C[(size_t)col * M + mbase] = vv;
      }
    return;
  }
  #pragma unroll
  for (int i = 0; i < 2; ++i)
    #pragma unroll
    for (int j = 0; j < 2; ++j)
      #pragma unroll
      for (int r = 0; r < 4; ++r) {
        int mrow = m0 + wm * 32 + i * 16 + quad * 4 + r;
        int col = n0 + wn * 32 + j * 16 + l16;
        float val = acc[i][j][r];
        if (MODE == 0) {
          size_t idx = (size_t)mrow * N + col;
          C[idx] = val + (addend ? addend[idx] : 0.0f);
        } else if (mrow < cnt) {
          int slot = list[mrow];
          if (MODE == 1) {
            float uu = acc2[i][j][r];
            float hv = val / (1.0f + __expf(-val)) * uu;  // silu(g)*u
            C[(size_t)slot * N + col] = hv;
          } else {
            C[(size_t)slot * N + col] = val * gatebuf[slot];
          }
        }
      }
}

// ---------------- flash attention: split-bf16 MFMA, 32x32 tiles ----------------
// Q: fragments in registers (global->reg once, split bf16).
// K: LDS row-major [32][136] u16 hi/lo -> QK B-frags via ds_read_b128.
// V: consumed from V^T global layout [512][2048] (produced by gemm MODE 3);
//    staged as Vt[d 0..127][kv 0..31] in [128][40] u16 hi/lo -> PV B-frags via
//    contiguous ds_read_b128 (same pattern as K).
// P: LDS [32][40] u16 hi/lo (written by softmax pass) -> PV A-frags via b128.
__global__ __launch_bounds__(256) void flash_kernel(
    const float* __restrict__ Q, const float* __restrict__ Kb,
    const float* __restrict__ VbT, float* __restrict__ Ob) {
  __shared__ __attribute__((aligned(16))) u16b Khi[32 * 136];
  __shared__ __attribute__((aligned(16))) u16b Klo[32 * 136];
  __shared__ __attribute__((aligned(16))) u16b Vthi[128 * 40];
  __shared__ __attribute__((aligned(16))) u16b Vtlo[128 * 40];
  __shared__ float Ss[32 * 36];
  __shared__ __attribute__((aligned(16))) u16b Phi[32 * 40];
  __shared__ __attribute__((aligned(16))) u16b Plo[32 * 40];
  __shared__ float red[32 * 8];
  __shared__ float mrow[32], lrow[32], arow[32];

  int qt = (gridDim.x - 1) - blockIdx.x;  // big tiles first
  int h = blockIdx.y;
  int g = h >> 2;  // GQA: 4 q-heads per kv-head
  int tid = threadIdx.x;
  int wave = tid >> 6, lane = tid & 63;
  int l16 = lane & 15, quad = lane >> 4;
  int sm = wave >> 1, sn = wave & 1;  // S subtile (sm,sn); PV rows sm*16, d-half sn

  // --- Q fragments (split bf16) in registers: row sm*16+l16, k = kc*32+quad*8 ---
  s8v qhi[4], qlo[4];
  {
    const float* qp = Q + (size_t)(qt * 32 + sm * 16 + l16) * 2048 + h * 128 + quad * 8;
    #pragma unroll
    for (int kc = 0; kc < 4; ++kc) {
      float4 f0 = *(const float4*)(qp + kc * 32);
      float4 f1 = *(const float4*)(qp + kc * 32 + 4);
      float f[8] = {f0.x, f0.y, f0.z, f0.w, f1.x, f1.y, f1.z, f1.w};
      u16b hi[8], lo[8];
      #pragma unroll
      for (int x = 0; x < 8; ++x) split2(f[x], hi[x], lo[x]);
      FragCvt ch, cl;
      ch.q[0] = pack4(hi); ch.q[1] = pack4(hi + 4);
      cl.q[0] = pack4(lo); cl.q[1] = pack4(lo + 4);
      qhi[kc] = ch.v; qlo[kc] = cl.v;
    }
  }

  if (tid < 32) { mrow[tid] = -1e30f; lrow[tid] = 0.f; }

  f4v o[4];
  #pragma unroll
  for (int db = 0; db < 4; ++db) o[db] = (f4v)0.0f;

  int krow = tid >> 3, ksk = (tid & 7) * 16;  // K staging: row 0..31, 16 d each
  int vd = tid >> 1, vk0 = (tid & 1) * 16;    // V staging: d 0..127, 16 kv each
  int sr = tid >> 3, sp = tid & 7;            // softmax mapping

  const u16b* krow_h = &Khi[(sn * 16 + l16) * 136];
  const u16b* krow_l = &Klo[(sn * 16 + l16) * 136];

  for (int kt = 0; kt <= qt; ++kt) {
    __syncthreads();
    // ---- stage K (padded row-major) and V^T (padded row-major), split bf16 ----
    {
      const float* ks = Kb + (size_t)(kt * 32 + krow) * 512 + g * 128 + ksk;
      int kb = krow * 136 + ksk;
      #pragma unroll
      for (int half = 0; half < 2; ++half) {
        float4 f0 = *(const float4*)(ks + half * 8);
        float4 f1 = *(const float4*)(ks + half * 8 + 4);
        float f[8] = {f0.x, f0.y, f0.z, f0.w, f1.x, f1.y, f1.z, f1.w};
        u16b hi[8], lo[8];
        #pragma unroll
        for (int x = 0; x < 8; ++x) split2(f[x], hi[x], lo[x]);
        *(unsigned long long*)&Khi[kb + half * 8]     = pack4(hi);
        *(unsigned long long*)&Khi[kb + half * 8 + 4] = pack4(hi + 4);
        *(unsigned long long*)&Klo[kb + half * 8]     = pack4(lo);
        *(unsigned long long*)&Klo[kb + half * 8 + 4] = pack4(lo + 4);
      }
      const float* vs = VbT + (size_t)(g * 128 + vd) * 2048 + kt * 32 + vk0;
      int vb = vd * 40 + vk0;
      #pragma unroll
      for (int half = 0; half < 2; ++half) {
        float4 f0 = *(const float4*)(vs + half * 8);
        float4 f1 = *(const float4*)(vs + half * 8 + 4);
        float f[8] = {f0.x, f0.y, f0.z, f0.w, f1.x, f1.y, f1.z, f1.w};
        u16b hi[8], lo[8];
        #pragma unroll
        for (int x = 0; x < 8; ++x) split2(f[x], hi[x], lo[x]);
        *(unsigned long long*)&Vthi[vb + half * 8]     = pack4(hi);
        *(unsigned long long*)&Vthi[vb + half * 8 + 4] = pack4(hi + 4);
        *(unsigned long long*)&Vtlo[vb + half * 8]     = pack4(lo);
        *(unsigned long long*)&Vtlo[vb + half * 8 + 4] = pack4(lo + 4);
      }
    }
    __syncthreads();
    // ---- S = Q K^T via MFMA (3-term split) ----
    f4v a0 = (f4v)0.0f, a1 = (f4v)0.0f, a2 = (f4v)0.0f;
    __builtin_amdgcn_s_setprio(1);
    #pragma unroll
    for (int kc = 0; kc < 4; ++kc) {
      s8v kh = *(const s8v*)(krow_h + kc * 32 + quad * 8);
      s8v kl = *(const s8v*)(krow_l + kc * 32 + quad * 8);
      a0 = mfma_b(qhi[kc], kh, a0);
      a1 = mfma_b(qhi[kc], kl, a1);
      a2 = mfma_b(qlo[kc], kh, a2);
    }
    __builtin_amdgcn_s_setprio(0);
    {
      f4v sacc = a0 + a1 + a2;
      const float sc = 0.08838834764831845f;  // 1/sqrt(128)
      #pragma unroll
      for (int r = 0; r < 4; ++r) {
        int row_l = sm * 16 + quad * 4 + r;
        int col_l = sn * 16 + l16;
        int qb = qt * 32 + row_l, kb2 = kt * 32 + col_l;
        Ss[row_l * 36 + col_l] = (kb2 <= qb) ? sacc[r] * sc : -1e30f;
      }
    }
    __syncthreads();
    // ---- online softmax ----
    float mx = -3e38f;
    #pragma unroll
    for (int c = sp * 4; c < sp * 4 + 4; ++c) mx = fmaxf(mx, Ss[sr * 36 + c]);
    red[sr * 8 + sp] = mx;
    __syncthreads();
    if (sp == 0) {
      float mn = mrow[sr];
      #pragma unroll
      for (int p = 0; p < 8; ++p) mn = fmaxf(mn, red[sr * 8 + p]);
      arow[sr] = __expf(mrow[sr] - mn);
      mrow[sr] = mn;
    }
    __syncthreads();
    {
      float m = mrow[sr];
      float sum = 0.f;
      #pragma unroll
      for (int c = sp * 4; c < sp * 4 + 4; ++c) {
        float e2 = __expf(Ss[sr * 36 + c] - m);
        u16b eh, el;
        split2(e2, eh, el);
        Phi[sr * 40 + c] = eh;
        Plo[sr * 40 + c] = el;
        sum += e2;
      }
      red[sr * 8 + sp] = sum;
    }
    __syncthreads();
    if (sp == 0) {
      float s2 = 0.f;
      #pragma unroll
      for (int p = 0; p < 8; ++p) s2 += red[sr * 8 + p];
      lrow[sr] = lrow[sr] * arow[sr] + s2;
    }
    // ---- PV via MFMA (rescale, then O += P V) ----
    {
      f4v arv;
      arv[0] = arow[sm * 16 + quad * 4 + 0];
      arv[1] = arow[sm * 16 + quad * 4 + 1];
      arv[2] = arow[sm * 16 + quad * 4 + 2];
      arv[3] = arow[sm * 16 + quad * 4 + 3];
      #pragma unroll
      for (int db = 0; db < 4; ++db) o[db] *= arv;

      s8v pah = *(const s8v*)&Phi[(sm * 16 + l16) * 40 + quad * 8];
      s8v pal = *(const s8v*)&Plo[(sm * 16 + l16) * 40 + quad * 8];
      __builtin_amdgcn_s_setprio(1);
      #pragma unroll
      for (int db = 0; db < 4; ++db) {
        int vrow = sn * 64 + db * 16 + l16;
        s8v vh = *(const s8v*)&Vthi[vrow * 40 + quad * 8];
        s8v vl = *(const s8v*)&Vtlo[vrow * 40 + quad * 8];
        o[db] = mfma_b(pah, vh, o[db]);
        o[db] = mfma_b(pah, vl, o[db]);
        o[db] = mfma_b(pal, vh, o[db]);
      }
      __builtin_amdgcn_s_setprio(0);
    }
  }
  __syncthreads();
  {
    int row0 = sm * 16 + quad * 4;
    f4v invv;
    invv[0] = 1.f / lrow[row0 + 0];
    invv[1] = 1.f / lrow[row0 + 1];
    invv[2] = 1.f / lrow[row0 + 2];
    invv[3] = 1.f / lrow[row0 + 3];
    #pragma unroll
    for (int db = 0; db < 4; ++db) o[db] *= invv;
    #pragma unroll
    for (int r = 0; r < 4; ++r) {
      float* ob = Ob + (size_t)(qt * 32 + row0 + r) * 2048 + h * 128 + sn * 64 + l16;
      ob[0]  = o[0][r];
      ob[16] = o[1][r];
      ob[32] = o[2][r];
      ob[48] = o[3][r];
    }
  }
}

// ---------------- router: logits (f32 exact), top-2, gates, expert lists ----------------
__global__ __launch_bounds__(256) void router_kernel(
    const float* __restrict__ xn2, const float* __restrict__ rw,
    int* __restrict__ counts, int* __restrict__ list, float* __restrict__ gatebuf) {
  __shared__ float red[256];
  __shared__ float logits[16];
  int t = blockIdx.x, tid = threadIdx.x;
  int e = tid >> 4, p = tid & 15;
  const float* xr = xn2 + (size_t)t * HID;
  float s = 0.f;
  for (int j = p * 128; j < p * 128 + 128; ++j) s += xr[j] * rw[j * 16 + e];
  red[tid] = s;
  __syncthreads();
  if (tid < 16) {
    float l = 0.f;
    #pragma unroll
    for (int p2 = 0; p2 < 16; ++p2) l += red[tid * 16 + p2];
    logits[tid] = l;
  }
  __syncthreads();
  if (tid == 0) {
    int i0 = 0; float l0 = logits[0];
    for (int i = 1; i < 16; ++i) if (logits[i] > l0) { l0 = logits[i]; i0 = i; }
    int i1 = -1; float l1 = -3e38f;
    for (int i = 0; i < 16; ++i) if (i != i0 && logits[i] > l1) { l1 = logits[i]; i1 = i; }
    float g0 = 1.f / (1.f + __expf(l1 - l0));
    float g1 = 1.f - g0;
    int s0 = atomicAdd(&counts[i0], 1);
    list[i0 * T_TOK + s0] = t * 2;
    gatebuf[t * 2] = g0;
    int s1 = atomicAdd(&counts[i1], 1);
    list[i1 * T_TOK + s1] = t * 2 + 1;
    gatebuf[t * 2 + 1] = g1;
  }
}

// ---------------- final: sum expert slots + residual, RMS, f32 out ----------------
__global__ __launch_bounds__(256) void final_kernel(
    const float* __restrict__ moeout, const float* __restrict__ resid,
    const float* __restrict__ W, float* __restrict__ out) {
  __shared__ float lds[4];
  int t = blockIdx.x, tid = threadIdx.x;
  const float* m0 = moeout + (size_t)(2 * t) * HID;
  const float* m1 = moeout + (size_t)(2 * t + 1) * HID;
  const float* rr = resid + (size_t)t * HID;
  float v[8]; float ss = 0.f;
  #pragma unroll
  for (int i = 0; i < 8; ++i) {
    int j = tid + i * 256;
    v[i] = m0[j] + m1[j] + rr[j];
    ss += v[i] * v[i];
  }
  float tot = blk_sum_256(ss, lds);
  float scale = rsqrtf(tot * (1.f / (float)HID) + 1e-6f);
  float* orow = out + (size_t)t * HID;
  #pragma unroll
  for (int i = 0; i < 8; ++i) {
    int j = tid + i * 256;
    orow[j] = v[i] * scale * (1.f + W[j]);
  }
}

extern "C" void kernel_launch(void* const* d_in, const int* in_sizes, int n_in,
                              void* d_out, int out_size, void* d_ws, size_t ws_size,
                              hipStream_t stream) {
  const int* input_ids   = (const int*)d_in[0];
  const int* positions   = (const int*)d_in[1];
  const float* hidden    = (const float*)d_in[2];
  // d_in[3] spec_step_idx: unused by reference
  const float* embed_w   = (const float*)d_in[4];
  const float* fc_w      = (const float*)d_in[5];
  const float* pre_emb   = (const float*)d_in[6];
  const float* pre_hid   = (const float*)d_in[7];
  const float* in_ln     = (const float*)d_in[8];
  const float* post_ln   = (const float*)d_in[9];
  const float* final_w   = (const float*)d_in[10];
  const float* wq        = (const float*)d_in[11];
  const float* wk        = (const float*)d_in[12];
  const float* wv        = (const float*)d_in[13];
  const float* wo        = (const float*)d_in[14];
  const float* qnw       = (const float*)d_in[15];
  const float* knw       = (const float*)d_in[16];
  const float* rw        = (const float*)d_in[17];
  const float* wg        = (const float*)d_in[18];
  const float* wu        = (const float*)d_in[19];
  const float* wd        = (const float*)d_in[20];

  char* ws = (char*)d_ws;
  float* cat    = (float*)(ws + 0);           // 32 MB (T x 4096)
  float* x      = (float*)(ws + 33554432);    // 16 MB fc out / residual1
  float* xn     = (float*)(ws + 50331648);    // 16 MB
  float* q      = (float*)(ws + 67108864);    // 16 MB
  float* kbuf   = (float*)(ws + 83886080);    // 4 MB
  float* vbufT  = (float*)(ws + 88080384);    // 4 MB (V^T: 512 x 2048 f32)
  float* attn   = (float*)(ws + 92274688);    // 16 MB
  float* x2     = (float*)(ws + 109051904);   // 16 MB residual2
  float* xn2    = (float*)(ws + 125829120);   // 16 MB
  int*   counts = (int*)(ws + 142606336);     // 64 B
  int*   list   = (int*)(ws + 142606592);     // 128 KB
  float* gateb  = (float*)(ws + 142737664);   // 16 KB
  float* hbuf   = q;    // alias: q dead after attention (4096 x 1024 f32 = 16 MB)
  float* moeout = cat;  // alias: cat dead after fc (4096 x 2048 f32 = 32 MB)

  zero_counts_kernel<<<1, 64, 0, stream>>>(counts);
  embed_cat_kernel<<<dim3(2048, 2), 256, 0, stream>>>(input_ids, embed_w, hidden,
                                                      pre_emb, pre_hid, cat);
  gemm_k<0><<<dim3(32, 32), 256, 0, stream>>>(cat, fc_w, nullptr, x, nullptr,
                                              nullptr, nullptr, nullptr, 2048, 2048, 4096);
  rms_f32_kernel<<<2048, 256, 0, stream>>>(x, in_ln, xn);
  gemm_k<0><<<dim3(32, 32), 256, 0, stream>>>(xn, wq, nullptr, q, nullptr,
                                              nullptr, nullptr, nullptr, 2048, 2048, 2048);
  gemm_k<0><<<dim3(8, 32), 256, 0, stream>>>(xn, wk, nullptr, kbuf, nullptr,
                                             nullptr, nullptr, nullptr, 2048, 512, 2048);
  gemm_k<3><<<dim3(8, 32), 256, 0, stream>>>(xn, wv, nullptr, vbufT, nullptr,
                                             nullptr, nullptr, nullptr, 2048, 512, 2048);
  qknorm_rope_kernel<<<dim3(2048, 16), 128, 0, stream>>>(q, qnw, positions, 2048);
  qknorm_rope_kernel<<<dim3(2048, 4), 128, 0, stream>>>(kbuf, knw, positions, 512);
  flash_kernel<<<dim3(64, 16), 256, 0, stream>>>(q, kbuf, vbufT, attn);
  gemm_k<0><<<dim3(32, 32), 256, 0, stream>>>(attn, wo, nullptr, x2, x,
                                              nullptr, nullptr, nullptr, 2048, 2048, 2048);
  rms_f32_kernel<<<2048, 256, 0, stream>>>(x2, post_ln, xn2);
  router_kernel<<<2048, 256, 0, stream>>>(xn2, rw, counts, list, gateb);
  gemm_k<1><<<dim3(16, 32, 16), 256, 0, stream>>>(xn2, wg, wu, hbuf, nullptr,
                                                  counts, list, nullptr, 0, 1024, 2048);
  gemm_k<2><<<dim3(32, 32, 16), 256, 0, stream>>>(hbuf, wd, nullptr, moeout, nullptr,
                                                  counts, list, gateb, 0, 2048, 1024);
  final_kernel<<<2048, 256, 0, stream>>>(moeout, x2, final_w, (float*)d_out);
}

// Round 3
// 1713.698 us; speedup vs baseline: 1.6679x; 1.2651x over previous
//
#include <hip/hip_runtime.h>
#include <cstddef>

// Qwen3.5 MTP layer, MI355X gfx950. Round 4: pre-split bf16 operands for dense GEMMs.
// T=2048 H=2048 V=32000 NH=16 NKV=4 DH=128 E=16 K=2 I=1024
// Dense GEMMs (fc, qkv, wo): A pre-split [hi|lo] bf16 (written by producers),
// B pre-transposed+split bf16 (tsplit_kernel once per launch). GEMM inner loop is
// pure bf16: no VALU conversion, no scatter stores. 3-term split (hh+hl+lh),
// identical accumulation order to round 2/3 -> same numerics (~2^-17 rel).
// MoE (gemm_k MODE 1/2), flash core, router: unchanged.

typedef unsigned short u16b;
typedef __attribute__((ext_vector_type(8))) short s8v;   // 8 x bf16 frag
typedef __attribute__((ext_vector_type(4))) float f4v;   // MFMA acc

#define T_TOK 2048
#define HID   2048

__device__ __forceinline__ float bf2f(u16b h) {
  return __uint_as_float(((unsigned int)h) << 16);
}
__device__ __forceinline__ u16b f2bf(float f) {
  unsigned int u = __float_as_uint(f);
  return (u16b)((u + 0x7fffu + ((u >> 16) & 1u)) >> 16);
}
__device__ __forceinline__ void split2(float f, u16b& hi, u16b& lo) {
  hi = f2bf(f);
  lo = f2bf(f - bf2f(hi));
}
__device__ __forceinline__ unsigned long long pack4(const u16b* p) {
  return (unsigned long long)p[0] | ((unsigned long long)p[1] << 16) |
         ((unsigned long long)p[2] << 32) | ((unsigned long long)p[3] << 48);
}
__device__ __forceinline__ f4v mfma_b(s8v a, s8v b, f4v c) {
  return __builtin_amdgcn_mfma_f32_16x16x32_bf16(a, b, c, 0, 0, 0);
}
union FragCvt { unsigned long long q[2]; s8v v; };

// block=256 sum-reduce
__device__ __forceinline__ float blk_sum_256(float v, float* lds4) {
  #pragma unroll
  for (int off = 32; off > 0; off >>= 1) v += __shfl_down(v, off);
  int tid = threadIdx.x;
  if ((tid & 63) == 0) lds4[tid >> 6] = v;
  __syncthreads();
  return lds4[0] + lds4[1] + lds4[2] + lds4[3];
}

// ---------------- zero counts ----------------
__global__ void zero_counts_kernel(int* counts) {
  if (threadIdx.x < 16) counts[threadIdx.x] = 0;
}

// ---------------- embed gather + RMS + concat -> split bf16 A' ----------------
// catp row t (ld 8192): cols [0,4096)=hi of [emb|hid], [4096,8192)=lo
__global__ __launch_bounds__(256) void embed_cat_kernel(
    const int* __restrict__ ids, const float* __restrict__ embw,
    const float* __restrict__ hid, const float* __restrict__ w_emb,
    const float* __restrict__ w_hid, u16b* __restrict__ catp) {
  __shared__ float lds[4];
  int t = blockIdx.x, which = blockIdx.y, tid = threadIdx.x;
  const float* src;
  const float* w;
  if (which == 0) { src = embw + (size_t)ids[t] * HID; w = w_emb; }
  else            { src = hid  + (size_t)t * HID;      w = w_hid; }
  u16b* dst = catp + (size_t)t * 8192 + which * 2048;
  float v[8]; float ss = 0.f;
  #pragma unroll
  for (int i = 0; i < 8; ++i) { v[i] = src[tid + i * 256]; ss += v[i] * v[i]; }
  float tot = blk_sum_256(ss, lds);
  float scale = rsqrtf(tot * (1.f / (float)HID) + 1e-6f);
  #pragma unroll
  for (int i = 0; i < 8; ++i) {
    int j = tid + i * 256;
    float val = v[i] * scale * (1.f + w[j]);
    u16b h, l;
    split2(val, h, l);
    dst[j] = h;
    dst[4096 + j] = l;
  }
}

// ---------------- RMS norm on f32 rows -> f32 out ----------------
__global__ __launch_bounds__(256) void rms_f32_kernel(
    const float* __restrict__ X, const float* __restrict__ W, float* __restrict__ Y) {
  __shared__ float lds[4];
  int t = blockIdx.x, tid = threadIdx.x;
  const float* row = X + (size_t)t * HID;
  float v[8]; float ss = 0.f;
  #pragma unroll
  for (int i = 0; i < 8; ++i) { v[i] = row[tid + i * 256]; ss += v[i] * v[i]; }
  float tot = blk_sum_256(ss, lds);
  float scale = rsqrtf(tot * (1.f / (float)HID) + 1e-6f);
  float* yrow = Y + (size_t)t * HID;
  #pragma unroll
  for (int i = 0; i < 8; ++i) {
    int j = tid + i * 256;
    yrow[j] = v[i] * scale * (1.f + W[j]);
  }
}

// ---------------- RMS norm -> split bf16 A' [hi|lo], ld 2*HID ----------------
__global__ __launch_bounds__(256) void rms_split_kernel(
    const float* __restrict__ X, const float* __restrict__ W, u16b* __restrict__ Yp) {
  __shared__ float lds[4];
  int t = blockIdx.x, tid = threadIdx.x;
  const float* row = X + (size_t)t * HID;
  float v[8]; float ss = 0.f;
  #pragma unroll
  for (int i = 0; i < 8; ++i) { v[i] = row[tid + i * 256]; ss += v[i] * v[i]; }
  float tot = blk_sum_256(ss, lds);
  float scale = rsqrtf(tot * (1.f / (float)HID) + 1e-6f);
  u16b* yrow = Yp + (size_t)t * (2 * HID);
  #pragma unroll
  for (int i = 0; i < 8; ++i) {
    int j = tid + i * 256;
    float val = v[i] * scale * (1.f + W[j]);
    u16b h, l;
    split2(val, h, l);
    yrow[j] = h;
    yrow[HID + j] = l;
  }
}

// ---------------- weight transpose + split: B f32 [K][N] -> Bt bf16 [N][2K] ----------------
// Bt[row_off+n][k] = hi(B[k][n]), Bt[row_off+n][Kf+k] = lo. grid (N/64, K/64).
__global__ __launch_bounds__(256) void tsplit_kernel(
    const float* __restrict__ B, u16b* __restrict__ Bt,
    int Kf, int N, int row_off) {
  __shared__ u16b ht[64][68];
  __shared__ u16b lt[64][68];
  int n0 = blockIdx.x * 64, k0 = blockIdx.y * 64;
  int tid = threadIdx.x;
  int kl = tid >> 4, nl = (tid & 15) * 4;
  #pragma unroll
  for (int p = 0; p < 4; ++p) {
    int kk = p * 16 + kl;
    float4 f = *(const float4*)&B[(size_t)(k0 + kk) * N + n0 + nl];
    float ff[4] = {f.x, f.y, f.z, f.w};
    #pragma unroll
    for (int j = 0; j < 4; ++j) {
      u16b h, l;
      split2(ff[j], h, l);
      ht[nl + j][kk] = h;
      lt[nl + j][kk] = l;
    }
  }
  __syncthreads();
  int ldo = 2 * Kf;
  int nr = tid >> 2, kc = (tid & 3) * 16;
  u16b* orow = Bt + (size_t)(row_off + n0 + nr) * ldo + k0 + kc;
  #pragma unroll
  for (int c = 0; c < 4; ++c) {
    *(unsigned long long*)(orow + c * 4)      = *(const unsigned long long*)&ht[nr][kc + c * 4];
    *(unsigned long long*)(orow + Kf + c * 4) = *(const unsigned long long*)&lt[nr][kc + c * 4];
  }
}

// ---------------- dense split-bf16 GEMM ----------------
// A' [M][2Kf] bf16 [hi|lo]; Bt [N][2Kf] bf16 [hi|lo] (pre-transposed weights).
// 64x64 tile, 4 waves, 2x2 16x16 frags/wave, 12 MFMAs per 32-k step (hh+hl+lh).
// EP 0: C[m][n] = acc (+addend). EP 1: qkv scatter (q / k / V^T by n-block).
template <int EP>
__global__ __launch_bounds__(256) void gemm_bs(
    const u16b* __restrict__ Ap, const u16b* __restrict__ Bp,
    float* __restrict__ C, const float* __restrict__ addend,
    float* __restrict__ kout, float* __restrict__ vtout,
    int M, int N, int Kf) {
  __shared__ __attribute__((aligned(16))) u16b Ahs[64 * 40];
  __shared__ __attribute__((aligned(16))) u16b Als[64 * 40];
  __shared__ __attribute__((aligned(16))) u16b Bhs[64 * 40];
  __shared__ __attribute__((aligned(16))) u16b Bls[64 * 40];
  int n0 = blockIdx.x * 64, m0 = blockIdx.y * 64;
  int tid = threadIdx.x;
  int wave = tid >> 6, lane = tid & 63;
  int wm = wave >> 1, wn = wave & 1;
  int l16 = lane & 15, quad = lane >> 4;
  int lda = 2 * Kf;
  int sr = tid >> 2, skc = (tid & 3) * 8;
  const u16b* apH = Ap + (size_t)(m0 + sr) * lda + skc;
  const u16b* bpH = Bp + (size_t)(n0 + sr) * lda + skc;
  int sb = sr * 40 + skc;

  f4v acc[2][2];
  #pragma unroll
  for (int i = 0; i < 2; ++i)
    #pragma unroll
    for (int j = 0; j < 2; ++j) acc[i][j] = (f4v)0.0f;

  for (int k0 = 0; k0 < Kf; k0 += 32) {
    // issue loads early (overlap with previous iteration's MFMA tail)
    s8v ta = *(const s8v*)(apH + k0);
    s8v tb = *(const s8v*)(apH + Kf + k0);
    s8v tc = *(const s8v*)(bpH + k0);
    s8v td = *(const s8v*)(bpH + Kf + k0);
    __syncthreads();
    FragCvt u;
    u.v = ta;
    *(unsigned long long*)&Ahs[sb]     = u.q[0];
    *(unsigned long long*)&Ahs[sb + 4] = u.q[1];
    u.v = tb;
    *(unsigned long long*)&Als[sb]     = u.q[0];
    *(unsigned long long*)&Als[sb + 4] = u.q[1];
    u.v = tc;
    *(unsigned long long*)&Bhs[sb]     = u.q[0];
    *(unsigned long long*)&Bhs[sb + 4] = u.q[1];
    u.v = td;
    *(unsigned long long*)&Bls[sb]     = u.q[0];
    *(unsigned long long*)&Bls[sb + 4] = u.q[1];
    __syncthreads();
    s8v a0  = *(const s8v*)&Ahs[(wm * 32 + l16) * 40 + quad * 8];
    s8v a1  = *(const s8v*)&Ahs[(wm * 32 + 16 + l16) * 40 + quad * 8];
    s8v b0  = *(const s8v*)&Bhs[(wn * 32 + l16) * 40 + quad * 8];
    s8v b1  = *(const s8v*)&Bhs[(wn * 32 + 16 + l16) * 40 + quad * 8];
    s8v a0l = *(const s8v*)&Als[(wm * 32 + l16) * 40 + quad * 8];
    s8v a1l = *(const s8v*)&Als[(wm * 32 + 16 + l16) * 40 + quad * 8];
    s8v b0l = *(const s8v*)&Bls[(wn * 32 + l16) * 40 + quad * 8];
    s8v b1l = *(const s8v*)&Bls[(wn * 32 + 16 + l16) * 40 + quad * 8];
    acc[0][0] = mfma_b(a0, b0, acc[0][0]);
    acc[0][1] = mfma_b(a0, b1, acc[0][1]);
    acc[1][0] = mfma_b(a1, b0, acc[1][0]);
    acc[1][1] = mfma_b(a1, b1, acc[1][1]);
    acc[0][0] = mfma_b(a0, b0l, acc[0][0]);
    acc[0][1] = mfma_b(a0, b1l, acc[0][1]);
    acc[1][0] = mfma_b(a1, b0l, acc[1][0]);
    acc[1][1] = mfma_b(a1, b1l, acc[1][1]);
    acc[0][0] = mfma_b(a0l, b0, acc[0][0]);
    acc[0][1] = mfma_b(a0l, b1, acc[0][1]);
    acc[1][0] = mfma_b(a1l, b0, acc[1][0]);
    acc[1][1] = mfma_b(a1l, b1, acc[1][1]);
  }

  if (EP == 0) {
    #pragma unroll
    for (int i = 0; i < 2; ++i)
      #pragma unroll
      for (int j = 0; j < 2; ++j)
        #pragma unroll
        for (int r = 0; r < 4; ++r) {
          int mrow = m0 + wm * 32 + i * 16 + quad * 4 + r;
          int col = n0 + wn * 32 + j * 16 + l16;
          size_t idx = (size_t)mrow * N + col;
          C[idx] = acc[i][j][r] + (addend ? addend[idx] : 0.0f);
        }
  } else {
    if (n0 < 2048) {  // q region
      #pragma unroll
      for (int i = 0; i < 2; ++i)
        #pragma unroll
        for (int j = 0; j < 2; ++j)
          #pragma unroll
          for (int r = 0; r < 4; ++r) {
            int mrow = m0 + wm * 32 + i * 16 + quad * 4 + r;
            int col = n0 + wn * 32 + j * 16 + l16;
            C[(size_t)mrow * 2048 + col] = acc[i][j][r];
          }
    } else if (n0 < 2560) {  // k region
      #pragma unroll
      for (int i = 0; i < 2; ++i)
        #pragma unroll
        for (int j = 0; j < 2; ++j)
          #pragma unroll
          for (int r = 0; r < 4; ++r) {
            int mrow = m0 + wm * 32 + i * 16 + quad * 4 + r;
            int col = n0 + wn * 32 + j * 16 + l16 - 2048;
            kout[(size_t)mrow * 512 + col] = acc[i][j][r];
          }
    } else {  // v region: write transposed V^T [512][2048]
      #pragma unroll
      for (int i = 0; i < 2; ++i)
        #pragma unroll
        for (int j = 0; j < 2; ++j) {
          int vrow = n0 + wn * 32 + j * 16 + l16 - 2560;
          int mbase = m0 + wm * 32 + i * 16 + quad * 4;
          float4 vv;
          vv.x = acc[i][j][0]; vv.y = acc[i][j][1];
          vv.z = acc[i][j][2]; vv.w = acc[i][j][3];
          *(float4*)&vtout[(size_t)vrow * 2048 + mbase] = vv;
        }
    }
  }
}

// ---------------- per-head RMS + RoPE (in place) ----------------
__global__ __launch_bounds__(128) void qknorm_rope_kernel(
    float* __restrict__ X, const float* __restrict__ W,
    const int* __restrict__ positions, int ld) {
  __shared__ float wsum[2];
  __shared__ float xs[128];
  __shared__ float sc;
  int t = blockIdx.x, hh = blockIdx.y, d = threadIdx.x;
  float* row = X + (size_t)t * ld + hh * 128;
  float x = row[d];
  float ss = x * x;
  #pragma unroll
  for (int off = 32; off > 0; off >>= 1) ss += __shfl_down(ss, off);
  if ((d & 63) == 0) wsum[d >> 6] = ss;
  __syncthreads();
  if (d == 0) sc = rsqrtf((wsum[0] + wsum[1]) * (1.f / 128.f) + 1e-6f);
  __syncthreads();
  float xn = x * sc * (1.f + W[d]);
  xs[d] = xn;
  __syncthreads();
  int pos = positions[t];
  int i = d & 63;
  // 1/theta^(i/64) = 2^(-i*log2(1e6)/64)
  float invf = exp2f((float)i * (-19.931568569324174f / 64.f));
  float ang = (float)pos * invf;
  float cv = cosf(ang), sv = sinf(ang);
  float other = xs[d ^ 64];
  row[d] = (d < 64) ? (xn * cv - other * sv) : (xn * cv + other * sv);
}

// ---------------- MoE MFMA GEMM (A,B f32 in memory), unchanged ----------------
// MODE 1: gathered gate/up (hi only): C h[slot] = silu(g)*u
// MODE 2: gathered down (hi only): C moeout[slot] = acc*gate[slot]
template <int MODE>
__global__ __launch_bounds__(256) void gemm_k(
    const float* __restrict__ A, const float* __restrict__ B,
    const float* __restrict__ B2, float* __restrict__ C,
    const float* __restrict__ addend, const int* __restrict__ counts,
    const int* __restrict__ list, const float* __restrict__ gatebuf,
    int M, int N, int K) {
  __shared__ u16b As[64 * 40];
  __shared__ u16b Bs[64 * 40];
  __shared__ u16b B2s[64 * 40];

  int n0 = blockIdx.x * 64;
  int m0 = blockIdx.y * 64;
  int e = blockIdx.z;
  int cnt = counts[e];
  if (m0 >= cnt) return;
  list += e * T_TOK;
  B += (size_t)e * K * N;
  if (MODE == 1) B2 += (size_t)e * K * N;

  int tid = threadIdx.x;
  int wave = tid >> 6, lane = tid & 63;
  int wm = wave >> 1, wn = wave & 1;
  int l16 = lane & 15, quad = lane >> 4;

  int am = tid >> 2, ak = (tid & 3) * 8;      // A stage: 64 rows x 32 k
  int bk = tid >> 3, bn = (tid & 7) * 8;      // B stage: 32 k x 64 n

  const float* aptr;
  {
    int mr = m0 + am;
    if (mr > cnt - 1) mr = cnt - 1;
    int entry = list[mr];
    int arow = (MODE == 1) ? (entry >> 1) : entry;
    aptr = A + (size_t)arow * K + ak;
  }
  const float* bptr = B + (size_t)bk * N + n0 + bn;
  const float* b2ptr = nullptr;
  if (MODE == 1) b2ptr = B2 + (size_t)bk * N + n0 + bn;

  f4v acc[2][2];
  f4v acc2[2][2];
  #pragma unroll
  for (int i = 0; i < 2; ++i)
    #pragma unroll
    for (int j = 0; j < 2; ++j) { acc[i][j] = (f4v)0.0f; acc2[i][j] = (f4v)0.0f; }

  for (int k0 = 0; k0 < K; k0 += 32) {
    __syncthreads();
    {
      const float* ap = aptr + k0;
      float4 f0 = *(const float4*)ap;
      float4 f1 = *(const float4*)(ap + 4);
      float f[8] = {f0.x, f0.y, f0.z, f0.w, f1.x, f1.y, f1.z, f1.w};
      u16b hi[8];
      #pragma unroll
      for (int x = 0; x < 8; ++x) hi[x] = f2bf(f[x]);
      *(unsigned long long*)&As[am * 40 + ak]     = pack4(hi);
      *(unsigned long long*)&As[am * 40 + ak + 4] = pack4(hi + 4);
    }
    {
      const float* bp = bptr + (size_t)k0 * N;
      float4 g0 = *(const float4*)bp;
      float4 g1 = *(const float4*)(bp + 4);
      float f[8] = {g0.x, g0.y, g0.z, g0.w, g1.x, g1.y, g1.z, g1.w};
      #pragma unroll
      for (int x = 0; x < 8; ++x) Bs[(bn + x) * 40 + bk] = f2bf(f[x]);
      if (MODE == 1) {
        const float* cp = b2ptr + (size_t)k0 * N;
        float4 h0 = *(const float4*)cp;
        float4 h1 = *(const float4*)(cp + 4);
        float f2[8] = {h0.x, h0.y, h0.z, h0.w, h1.x, h1.y, h1.z, h1.w};
        #pragma unroll
        for (int x = 0; x < 8; ++x) B2s[(bn + x) * 40 + bk] = f2bf(f2[x]);
      }
    }
    __syncthreads();
    s8v a0 = *(const s8v*)&As[(wm * 32 + l16) * 40 + quad * 8];
    s8v a1 = *(const s8v*)&As[(wm * 32 + 16 + l16) * 40 + quad * 8];
    s8v b0 = *(const s8v*)&Bs[(wn * 32 + l16) * 40 + quad * 8];
    s8v b1 = *(const s8v*)&Bs[(wn * 32 + 16 + l16) * 40 + quad * 8];
    acc[0][0] = mfma_b(a0, b0, acc[0][0]);
    acc[0][1] = mfma_b(a0, b1, acc[0][1]);
    acc[1][0] = mfma_b(a1, b0, acc[1][0]);
    acc[1][1] = mfma_b(a1, b1, acc[1][1]);
    if (MODE == 1) {
      s8v c0 = *(const s8v*)&B2s[(wn * 32 + l16) * 40 + quad * 8];
      s8v c1 = *(const s8v*)&B2s[(wn * 32 + 16 + l16) * 40 + quad * 8];
      acc2[0][0] = mfma_b(a0, c0, acc2[0][0]);
      acc2[0][1] = mfma_b(a0, c1, acc2[0][1]);
      acc2[1][0] = mfma_b(a1, c0, acc2[1][0]);
      acc2[1][1] = mfma_b(a1, c1, acc2[1][1]);
    }
  }

  #pragma unroll
  for (int i = 0; i < 2; ++i)
    #pragma unroll
    for (int j = 0; j < 2; ++j)
      #pragma unroll
      for (int r = 0; r < 4; ++r) {
        int mrow = m0 + wm * 32 + i * 16 + quad * 4 + r;
        int col = n0 + wn * 32 + j * 16 + l16;
        float val = acc[i][j][r];
        if (mrow < cnt) {
          int slot = list[mrow];
          if (MODE == 1) {
            float uu = acc2[i][j][r];
            float hv = val / (1.0f + __expf(-val)) * uu;  // silu(g)*u
            C[(size_t)slot * N + col] = hv;
          } else {
            C[(size_t)slot * N + col] = val * gatebuf[slot];
          }
        }
      }
}

// ---------------- flash attention: split-bf16 MFMA, 32x32 tiles ----------------
// Output written directly as split bf16 A' (attnp [T][4096]: [hi 2048 | lo 2048]).
__global__ __launch_bounds__(256) void flash_kernel(
    const float* __restrict__ Q, const float* __restrict__ Kb,
    const float* __restrict__ VbT, u16b* __restrict__ attnp) {
  __shared__ __attribute__((aligned(16))) u16b Khi[32 * 136];
  __shared__ __attribute__((aligned(16))) u16b Klo[32 * 136];
  __shared__ __attribute__((aligned(16))) u16b Vthi[128 * 40];
  __shared__ __attribute__((aligned(16))) u16b Vtlo[128 * 40];
  __shared__ float Ss[32 * 36];
  __shared__ __attribute__((aligned(16))) u16b Phi[32 * 40];
  __shared__ __attribute__((aligned(16))) u16b Plo[32 * 40];
  __shared__ float red[32 * 8];
  __shared__ float mrow[32], lrow[32], arow[32];

  int qt = (gridDim.x - 1) - blockIdx.x;  // big tiles first
  int h = blockIdx.y;
  int g = h >> 2;  // GQA: 4 q-heads per kv-head
  int tid = threadIdx.x;
  int wave = tid >> 6, lane = tid & 63;
  int l16 = lane & 15, quad = lane >> 4;
  int sm = wave >> 1, sn = wave & 1;

  // --- Q fragments (split bf16) in registers ---
  s8v qhi[4], qlo[4];
  {
    const float* qp = Q + (size_t)(qt * 32 + sm * 16 + l16) * 2048 + h * 128 + quad * 8;
    #pragma unroll
    for (int kc = 0; kc < 4; ++kc) {
      float4 f0 = *(const float4*)(qp + kc * 32);
      float4 f1 = *(const float4*)(qp + kc * 32 + 4);
      float f[8] = {f0.x, f0.y, f0.z, f0.w, f1.x, f1.y, f1.z, f1.w};
      u16b hi[8], lo[8];
      #pragma unroll
      for (int x = 0; x < 8; ++x) split2(f[x], hi[x], lo[x]);
      FragCvt ch, cl;
      ch.q[0] = pack4(hi); ch.q[1] = pack4(hi + 4);
      cl.q[0] = pack4(lo); cl.q[1] = pack4(lo + 4);
      qhi[kc] = ch.v; qlo[kc] = cl.v;
    }
  }

  if (tid < 32) { mrow[tid] = -1e30f; lrow[tid] = 0.f; }

  f4v o[4];
  #pragma unroll
  for (int db = 0; db < 4; ++db) o[db] = (f4v)0.0f;

  int krow = tid >> 3, ksk = (tid & 7) * 16;  // K staging
  int vd = tid >> 1, vk0 = (tid & 1) * 16;    // V staging
  int sr = tid >> 3, sp = tid & 7;            // softmax mapping

  const u16b* krow_h = &Khi[(sn * 16 + l16) * 136];
  const u16b* krow_l = &Klo[(sn * 16 + l16) * 136];

  for (int kt = 0; kt <= qt; ++kt) {
    __syncthreads();
    {
      const float* ks = Kb + (size_t)(kt * 32 + krow) * 512 + g * 128 + ksk;
      int kb = krow * 136 + ksk;
      #pragma unroll
      for (int half = 0; half < 2; ++half) {
        float4 f0 = *(const float4*)(ks + half * 8);
        float4 f1 = *(const float4*)(ks + half * 8 + 4);
        float f[8] = {f0.x, f0.y, f0.z, f0.w, f1.x, f1.y, f1.z, f1.w};
        u16b hi[8], lo[8];
        #pragma unroll
        for (int x = 0; x < 8; ++x) split2(f[x], hi[x], lo[x]);
        *(unsigned long long*)&Khi[kb + half * 8]     = pack4(hi);
        *(unsigned long long*)&Khi[kb + half * 8 + 4] = pack4(hi + 4);
        *(unsigned long long*)&Klo[kb + half * 8]     = pack4(lo);
        *(unsigned long long*)&Klo[kb + half * 8 + 4] = pack4(lo + 4);
      }
      const float* vs = VbT + (size_t)(g * 128 + vd) * 2048 + kt * 32 + vk0;
      int vb = vd * 40 + vk0;
      #pragma unroll
      for (int half = 0; half < 2; ++half) {
        float4 f0 = *(const float4*)(vs + half * 8);
        float4 f1 = *(const float4*)(vs + half * 8 + 4);
        float f[8] = {f0.x, f0.y, f0.z, f0.w, f1.x, f1.y, f1.z, f1.w};
        u16b hi[8], lo[8];
        #pragma unroll
        for (int x = 0; x < 8; ++x) split2(f[x], hi[x], lo[x]);
        *(unsigned long long*)&Vthi[vb + half * 8]     = pack4(hi);
        *(unsigned long long*)&Vthi[vb + half * 8 + 4] = pack4(hi + 4);
        *(unsigned long long*)&Vtlo[vb + half * 8]     = pack4(lo);
        *(unsigned long long*)&Vtlo[vb + half * 8 + 4] = pack4(lo + 4);
      }
    }
    __syncthreads();
    // ---- S = Q K^T via MFMA (3-term split) ----
    f4v a0 = (f4v)0.0f, a1 = (f4v)0.0f, a2 = (f4v)0.0f;
    __builtin_amdgcn_s_setprio(1);
    #pragma unroll
    for (int kc = 0; kc < 4; ++kc) {
      s8v kh = *(const s8v*)(krow_h + kc * 32 + quad * 8);
      s8v kl = *(const s8v*)(krow_l + kc * 32 + quad * 8);
      a0 = mfma_b(qhi[kc], kh, a0);
      a1 = mfma_b(qhi[kc], kl, a1);
      a2 = mfma_b(qlo[kc], kh, a2);
    }
    __builtin_amdgcn_s_setprio(0);
    {
      f4v sacc = a0 + a1 + a2;
      const float sc = 0.08838834764831845f;  // 1/sqrt(128)
      #pragma unroll
      for (int r = 0; r < 4; ++r) {
        int row_l = sm * 16 + quad * 4 + r;
        int col_l = sn * 16 + l16;
        int qb = qt * 32 + row_l, kb2 = kt * 32 + col_l;
        Ss[row_l * 36 + col_l] = (kb2 <= qb) ? sacc[r] * sc : -1e30f;
      }
    }
    __syncthreads();
    // ---- online softmax ----
    float mx = -3e38f;
    #pragma unroll
    for (int c = sp * 4; c < sp * 4 + 4; ++c) mx = fmaxf(mx, Ss[sr * 36 + c]);
    red[sr * 8 + sp] = mx;
    __syncthreads();
    if (sp == 0) {
      float mn = mrow[sr];
      #pragma unroll
      for (int p = 0; p < 8; ++p) mn = fmaxf(mn, red[sr * 8 + p]);
      arow[sr] = __expf(mrow[sr] - mn);
      mrow[sr] = mn;
    }
    __syncthreads();
    {
      float m = mrow[sr];
      float sum = 0.f;
      #pragma unroll
      for (int c = sp * 4; c < sp * 4 + 4; ++c) {
        float e2 = __expf(Ss[sr * 36 + c] - m);
        u16b eh, el;
        split2(e2, eh, el);
        Phi[sr * 40 + c] = eh;
        Plo[sr * 40 + c] = el;
        sum += e2;
      }
      red[sr * 8 + sp] = sum;
    }
    __syncthreads();
    if (sp == 0) {
      float s2 = 0.f;
      #pragma unroll
      for (int p = 0; p < 8; ++p) s2 += red[sr * 8 + p];
      lrow[sr] = lrow[sr] * arow[sr] + s2;
    }
    // ---- PV via MFMA ----
    {
      f4v arv;
      arv[0] = arow[sm * 16 + quad * 4 + 0];
      arv[1] = arow[sm * 16 + quad * 4 + 1];
      arv[2] = arow[sm * 16 + quad * 4 + 2];
      arv[3] = arow[sm * 16 + quad * 4 + 3];
      #pragma unroll
      for (int db = 0; db < 4; ++db) o[db] *= arv;

      s8v pah = *(const s8v*)&Phi[(sm * 16 + l16) * 40 + quad * 8];
      s8v pal = *(const s8v*)&Plo[(sm * 16 + l16) * 40 + quad * 8];
      __builtin_amdgcn_s_setprio(1);
      #pragma unroll
      for (int db = 0; db < 4; ++db) {
        int vrow = sn * 64 + db * 16 + l16;
        s8v vh = *(const s8v*)&Vthi[vrow * 40 + quad * 8];
        s8v vl = *(const s8v*)&Vtlo[vrow * 40 + quad * 8];
        o[db] = mfma_b(pah, vh, o[db]);
        o[db] = mfma_b(pah, vl, o[db]);
        o[db] = mfma_b(pal, vh, o[db]);
      }
      __builtin_amdgcn_s_setprio(0);
    }
  }
  __syncthreads();
  {
    int row0 = sm * 16 + quad * 4;
    f4v invv;
    invv[0] = 1.f / lrow[row0 + 0];
    invv[1] = 1.f / lrow[row0 + 1];
    invv[2] = 1.f / lrow[row0 + 2];
    invv[3] = 1.f / lrow[row0 + 3];
    #pragma unroll
    for (int db = 0; db < 4; ++db) o[db] *= invv;
    #pragma unroll
    for (int r = 0; r < 4; ++r) {
      u16b* ob = attnp + (size_t)(qt * 32 + row0 + r) * 4096 + h * 128 + sn * 64 + l16;
      #pragma unroll
      for (int db = 0; db < 4; ++db) {
        u16b hh, ll;
        split2(o[db][r], hh, ll);
        ob[db * 16] = hh;
        ob[2048 + db * 16] = ll;
      }
    }
  }
}

// ---------------- router ----------------
__global__ __launch_bounds__(256) void router_kernel(
    const float* __restrict__ xn2, const float* __restrict__ rw,
    int* __restrict__ counts, int* __restrict__ list, float* __restrict__ gatebuf) {
  __shared__ float red[256];
  __shared__ float logits[16];
  int t = blockIdx.x, tid = threadIdx.x;
  int e = tid >> 4, p = tid & 15;
  const float* xr = xn2 + (size_t)t * HID;
  float s = 0.f;
  for (int j = p * 128; j < p * 128 + 128; ++j) s += xr[j] * rw[j * 16 + e];
  red[tid] = s;
  __syncthreads();
  if (tid < 16) {
    float l = 0.f;
    #pragma unroll
    for (int p2 = 0; p2 < 16; ++p2) l += red[tid * 16 + p2];
    logits[tid] = l;
  }
  __syncthreads();
  if (tid == 0) {
    int i0 = 0; float l0 = logits[0];
    for (int i = 1; i < 16; ++i) if (logits[i] > l0) { l0 = logits[i]; i0 = i; }
    int i1 = -1; float l1 = -3e38f;
    for (int i = 0; i < 16; ++i) if (i != i0 && logits[i] > l1) { l1 = logits[i]; i1 = i; }
    float g0 = 1.f / (1.f + __expf(l1 - l0));
    float g1 = 1.f - g0;
    int s0 = atomicAdd(&counts[i0], 1);
    list[i0 * T_TOK + s0] = t * 2;
    gatebuf[t * 2] = g0;
    int s1 = atomicAdd(&counts[i1], 1);
    list[i1 * T_TOK + s1] = t * 2 + 1;
    gatebuf[t * 2 + 1] = g1;
  }
}

// ---------------- final ----------------
__global__ __launch_bounds__(256) void final_kernel(
    const float* __restrict__ moeout, const float* __restrict__ resid,
    const float* __restrict__ W, float* __restrict__ out) {
  __shared__ float lds[4];
  int t = blockIdx.x, tid = threadIdx.x;
  const float* m0 = moeout + (size_t)(2 * t) * HID;
  const float* m1 = moeout + (size_t)(2 * t + 1) * HID;
  const float* rr = resid + (size_t)t * HID;
  float v[8]; float ss = 0.f;
  #pragma unroll
  for (int i = 0; i < 8; ++i) {
    int j = tid + i * 256;
    v[i] = m0[j] + m1[j] + rr[j];
    ss += v[i] * v[i];
  }
  float tot = blk_sum_256(ss, lds);
  float scale = rsqrtf(tot * (1.f / (float)HID) + 1e-6f);
  float* orow = out + (size_t)t * HID;
  #pragma unroll
  for (int i = 0; i < 8; ++i) {
    int j = tid + i * 256;
    orow[j] = v[i] * scale * (1.f + W[j]);
  }
}

extern "C" void kernel_launch(void* const* d_in, const int* in_sizes, int n_in,
                              void* d_out, int out_size, void* d_ws, size_t ws_size,
                              hipStream_t stream) {
  const int* input_ids   = (const int*)d_in[0];
  const int* positions   = (const int*)d_in[1];
  const float* hidden    = (const float*)d_in[2];
  // d_in[3] spec_step_idx: unused by reference
  const float* embed_w   = (const float*)d_in[4];
  const float* fc_w      = (const float*)d_in[5];
  const float* pre_emb   = (const float*)d_in[6];
  const float* pre_hid   = (const float*)d_in[7];
  const float* in_ln     = (const float*)d_in[8];
  const float* post_ln   = (const float*)d_in[9];
  const float* final_w   = (const float*)d_in[10];
  const float* wq        = (const float*)d_in[11];
  const float* wk        = (const float*)d_in[12];
  const float* wv        = (const float*)d_in[13];
  const float* wo        = (const float*)d_in[14];
  const float* qnw       = (const float*)d_in[15];
  const float* knw       = (const float*)d_in[16];
  const float* rw        = (const float*)d_in[17];
  const float* wg        = (const float*)d_in[18];
  const float* wu        = (const float*)d_in[19];
  const float* wd        = (const float*)d_in[20];

  char* ws = (char*)d_ws;
  // region [0,32MB): catp (embed->fc) -> qkvw (fc->qkv) -> moeout (MoE->final)
  u16b*  catp   = (u16b*)(ws + 0);            // 2048 x 8192 bf16 = 32 MB
  u16b*  qkvw   = (u16b*)(ws + 0);            // 3072 x 4096 bf16 = 24 MB
  float* moeout = (float*)(ws + 0);           // 4096 x 2048 f32 = 32 MB
  float* x      = (float*)(ws + 33554432);    // 16 MB fc out / residual1
  // region [48MB,64MB): xnp (rms->qkv) -> wotw (qkv->wo)
  u16b*  xnp    = (u16b*)(ws + 50331648);     // 2048 x 4096 bf16 = 16 MB
  u16b*  wotw   = (u16b*)(ws + 50331648);     // 2048 x 4096 bf16 = 16 MB
  float* q      = (float*)(ws + 67108864);    // 16 MB; hbuf alias after flash
  float* kbuf   = (float*)(ws + 83886080);    // 4 MB
  float* vbufT  = (float*)(ws + 88080384);    // 4 MB (V^T: 512 x 2048 f32)
  // region [88MB,120MB): fctw (pre-fc) -> attnp (16MB @88MB) + x2 (16MB @104MB)
  u16b*  fctw   = (u16b*)(ws + 92274688);     // 2048 x 8192 bf16 = 32 MB
  u16b*  attnp  = (u16b*)(ws + 92274688);     // 2048 x 4096 bf16 = 16 MB
  float* x2     = (float*)(ws + 109051904);   // 16 MB residual2
  float* xn2    = (float*)(ws + 125829120);   // 16 MB
  int*   counts = (int*)(ws + 142606336);     // 64 B
  int*   list   = (int*)(ws + 142606592);     // 128 KB
  float* gateb  = (float*)(ws + 142737664);   // 16 KB
  float* hbuf   = q;    // alias: q dead after attention

  zero_counts_kernel<<<1, 64, 0, stream>>>(counts);
  embed_cat_kernel<<<dim3(2048, 2), 256, 0, stream>>>(input_ids, embed_w, hidden,
                                                      pre_emb, pre_hid, catp);
  tsplit_kernel<<<dim3(32, 64), 256, 0, stream>>>(fc_w, fctw, 4096, 2048, 0);
  gemm_bs<0><<<dim3(32, 32), 256, 0, stream>>>(catp, fctw, x, nullptr,
                                               nullptr, nullptr, 2048, 2048, 4096);
  // qkvw overlays catp (dead after fc gemm)
  tsplit_kernel<<<dim3(32, 32), 256, 0, stream>>>(wq, qkvw, 2048, 2048, 0);
  tsplit_kernel<<<dim3(8, 32), 256, 0, stream>>>(wk, qkvw, 2048, 512, 2048);
  tsplit_kernel<<<dim3(8, 32), 256, 0, stream>>>(wv, qkvw, 2048, 512, 2560);
  rms_split_kernel<<<2048, 256, 0, stream>>>(x, in_ln, xnp);
  gemm_bs<1><<<dim3(48, 32), 256, 0, stream>>>(xnp, qkvw, q, nullptr,
                                               kbuf, vbufT, 2048, 3072, 2048);
  // wotw overlays xnp (dead after qkv gemm)
  tsplit_kernel<<<dim3(32, 32), 256, 0, stream>>>(wo, wotw, 2048, 2048, 0);
  qknorm_rope_kernel<<<dim3(2048, 16), 128, 0, stream>>>(q, qnw, positions, 2048);
  qknorm_rope_kernel<<<dim3(2048, 4), 128, 0, stream>>>(kbuf, knw, positions, 512);
  flash_kernel<<<dim3(64, 16), 256, 0, stream>>>(q, kbuf, vbufT, attnp);
  gemm_bs<0><<<dim3(32, 32), 256, 0, stream>>>(attnp, wotw, x2, x,
                                               nullptr, nullptr, 2048, 2048, 2048);
  rms_f32_kernel<<<2048, 256, 0, stream>>>(x2, post_ln, xn2);
  router_kernel<<<2048, 256, 0, stream>>>(xn2, rw, counts, list, gateb);
  gemm_k<1><<<dim3(16, 32, 16), 256, 0, stream>>>(xn2, wg, wu, hbuf, nullptr,
                                                  counts, list, nullptr, 0, 1024, 2048);
  gemm_k<2><<<dim3(32, 32, 16), 256, 0, stream>>>(hbuf, wd, nullptr, moeout, nullptr,
                                                  counts, list, gateb, 0, 2048, 1024);
  final_kernel<<<2048, 256, 0, stream>>>(moeout, x2, final_w, (float*)d_out);
}

// Round 4
// 1541.079 us; speedup vs baseline: 1.8548x; 1.1120x over previous
//
#include <hip/hip_runtime.h>
#include <cstddef>

// Qwen3.5 MTP layer, MI355X gfx950. Round 5: restructured MoE GEMMs.
// T=2048 H=2048 V=32000 NH=16 NKV=4 DH=128 E=16 K=2 I=1024
// Dense GEMMs (fc, qkv, wo): pre-split bf16 A (producers) x pre-transposed split
// bf16 B (tsplit), 3-term hi/lo -> ~2^-17 rel error. Flash: split-bf16 MFMA.
// MoE: single bf16; A read as bf16 directly (xnp hi / bf16 h), 128x64 tiles,
// XOR-chunk-swizzled B transpose staging (kills 8-way write conflicts).

typedef unsigned short u16b;
typedef __attribute__((ext_vector_type(8))) short s8v;   // 8 x bf16 frag
typedef __attribute__((ext_vector_type(4))) float f4v;   // MFMA acc

#define T_TOK 2048
#define HID   2048

__device__ __forceinline__ float bf2f(u16b h) {
  return __uint_as_float(((unsigned int)h) << 16);
}
__device__ __forceinline__ u16b f2bf(float f) {
  unsigned int u = __float_as_uint(f);
  return (u16b)((u + 0x7fffu + ((u >> 16) & 1u)) >> 16);
}
__device__ __forceinline__ void split2(float f, u16b& hi, u16b& lo) {
  hi = f2bf(f);
  lo = f2bf(f - bf2f(hi));
}
__device__ __forceinline__ unsigned long long pack4(const u16b* p) {
  return (unsigned long long)p[0] | ((unsigned long long)p[1] << 16) |
         ((unsigned long long)p[2] << 32) | ((unsigned long long)p[3] << 48);
}
__device__ __forceinline__ f4v mfma_b(s8v a, s8v b, f4v c) {
  return __builtin_amdgcn_mfma_f32_16x16x32_bf16(a, b, c, 0, 0, 0);
}
union FragCvt { unsigned long long q[2]; s8v v; };

// block=256 sum-reduce
__device__ __forceinline__ float blk_sum_256(float v, float* lds4) {
  #pragma unroll
  for (int off = 32; off > 0; off >>= 1) v += __shfl_down(v, off);
  int tid = threadIdx.x;
  if ((tid & 63) == 0) lds4[tid >> 6] = v;
  __syncthreads();
  return lds4[0] + lds4[1] + lds4[2] + lds4[3];
}

// ---------------- zero counts ----------------
__global__ void zero_counts_kernel(int* counts) {
  if (threadIdx.x < 16) counts[threadIdx.x] = 0;
}

// ---------------- embed gather + RMS + concat -> split bf16 A' ----------------
// catp row t (ld 8192): cols [0,4096)=hi of [emb|hid], [4096,8192)=lo
__global__ __launch_bounds__(256) void embed_cat_kernel(
    const int* __restrict__ ids, const float* __restrict__ embw,
    const float* __restrict__ hid, const float* __restrict__ w_emb,
    const float* __restrict__ w_hid, u16b* __restrict__ catp) {
  __shared__ float lds[4];
  int t = blockIdx.x, which = blockIdx.y, tid = threadIdx.x;
  const float* src;
  const float* w;
  if (which == 0) { src = embw + (size_t)ids[t] * HID; w = w_emb; }
  else            { src = hid  + (size_t)t * HID;      w = w_hid; }
  u16b* dst = catp + (size_t)t * 8192 + which * 2048;
  float v[8]; float ss = 0.f;
  #pragma unroll
  for (int i = 0; i < 8; ++i) { v[i] = src[tid + i * 256]; ss += v[i] * v[i]; }
  float tot = blk_sum_256(ss, lds);
  float scale = rsqrtf(tot * (1.f / (float)HID) + 1e-6f);
  #pragma unroll
  for (int i = 0; i < 8; ++i) {
    int j = tid + i * 256;
    float val = v[i] * scale * (1.f + w[j]);
    u16b h, l;
    split2(val, h, l);
    dst[j] = h;
    dst[4096 + j] = l;
  }
}

// ---------------- RMS norm on f32 rows -> f32 out ----------------
__global__ __launch_bounds__(256) void rms_f32_kernel(
    const float* __restrict__ X, const float* __restrict__ W, float* __restrict__ Y) {
  __shared__ float lds[4];
  int t = blockIdx.x, tid = threadIdx.x;
  const float* row = X + (size_t)t * HID;
  float v[8]; float ss = 0.f;
  #pragma unroll
  for (int i = 0; i < 8; ++i) { v[i] = row[tid + i * 256]; ss += v[i] * v[i]; }
  float tot = blk_sum_256(ss, lds);
  float scale = rsqrtf(tot * (1.f / (float)HID) + 1e-6f);
  float* yrow = Y + (size_t)t * HID;
  #pragma unroll
  for (int i = 0; i < 8; ++i) {
    int j = tid + i * 256;
    yrow[j] = v[i] * scale * (1.f + W[j]);
  }
}

// ---------------- RMS norm -> split bf16 A' [hi|lo], ld 2*HID ----------------
__global__ __launch_bounds__(256) void rms_split_kernel(
    const float* __restrict__ X, const float* __restrict__ W, u16b* __restrict__ Yp) {
  __shared__ float lds[4];
  int t = blockIdx.x, tid = threadIdx.x;
  const float* row = X + (size_t)t * HID;
  float v[8]; float ss = 0.f;
  #pragma unroll
  for (int i = 0; i < 8; ++i) { v[i] = row[tid + i * 256]; ss += v[i] * v[i]; }
  float tot = blk_sum_256(ss, lds);
  float scale = rsqrtf(tot * (1.f / (float)HID) + 1e-6f);
  u16b* yrow = Yp + (size_t)t * (2 * HID);
  #pragma unroll
  for (int i = 0; i < 8; ++i) {
    int j = tid + i * 256;
    float val = v[i] * scale * (1.f + W[j]);
    u16b h, l;
    split2(val, h, l);
    yrow[j] = h;
    yrow[HID + j] = l;
  }
}

// ---------------- weight transpose + split: B f32 [K][N] -> Bt bf16 [N][2K] ----------------
__global__ __launch_bounds__(256) void tsplit_kernel(
    const float* __restrict__ B, u16b* __restrict__ Bt,
    int Kf, int N, int row_off) {
  __shared__ u16b ht[64][68];
  __shared__ u16b lt[64][68];
  int n0 = blockIdx.x * 64, k0 = blockIdx.y * 64;
  int tid = threadIdx.x;
  int kl = tid >> 4, nl = (tid & 15) * 4;
  #pragma unroll
  for (int p = 0; p < 4; ++p) {
    int kk = p * 16 + kl;
    float4 f = *(const float4*)&B[(size_t)(k0 + kk) * N + n0 + nl];
    float ff[4] = {f.x, f.y, f.z, f.w};
    #pragma unroll
    for (int j = 0; j < 4; ++j) {
      u16b h, l;
      split2(ff[j], h, l);
      ht[nl + j][kk] = h;
      lt[nl + j][kk] = l;
    }
  }
  __syncthreads();
  int ldo = 2 * Kf;
  int nr = tid >> 2, kc = (tid & 3) * 16;
  u16b* orow = Bt + (size_t)(row_off + n0 + nr) * ldo + k0 + kc;
  #pragma unroll
  for (int c = 0; c < 4; ++c) {
    *(unsigned long long*)(orow + c * 4)      = *(const unsigned long long*)&ht[nr][kc + c * 4];
    *(unsigned long long*)(orow + Kf + c * 4) = *(const unsigned long long*)&lt[nr][kc + c * 4];
  }
}

// ---------------- dense split-bf16 GEMM ----------------
// A' [M][2Kf] bf16 [hi|lo]; Bt [N][2Kf] bf16 [hi|lo] (pre-transposed weights).
// EP 0: C[m][n] = acc (+addend). EP 1: qkv scatter (q / k / V^T by n-block).
template <int EP>
__global__ __launch_bounds__(256) void gemm_bs(
    const u16b* __restrict__ Ap, const u16b* __restrict__ Bp,
    float* __restrict__ C, const float* __restrict__ addend,
    float* __restrict__ kout, float* __restrict__ vtout,
    int M, int N, int Kf) {
  __shared__ __attribute__((aligned(16))) u16b Ahs[64 * 40];
  __shared__ __attribute__((aligned(16))) u16b Als[64 * 40];
  __shared__ __attribute__((aligned(16))) u16b Bhs[64 * 40];
  __shared__ __attribute__((aligned(16))) u16b Bls[64 * 40];
  int n0 = blockIdx.x * 64, m0 = blockIdx.y * 64;
  int tid = threadIdx.x;
  int wave = tid >> 6, lane = tid & 63;
  int wm = wave >> 1, wn = wave & 1;
  int l16 = lane & 15, quad = lane >> 4;
  int lda = 2 * Kf;
  int sr = tid >> 2, skc = (tid & 3) * 8;
  const u16b* apH = Ap + (size_t)(m0 + sr) * lda + skc;
  const u16b* bpH = Bp + (size_t)(n0 + sr) * lda + skc;
  int sb = sr * 40 + skc;

  f4v acc[2][2];
  #pragma unroll
  for (int i = 0; i < 2; ++i)
    #pragma unroll
    for (int j = 0; j < 2; ++j) acc[i][j] = (f4v)0.0f;

  for (int k0 = 0; k0 < Kf; k0 += 32) {
    s8v ta = *(const s8v*)(apH + k0);
    s8v tb = *(const s8v*)(apH + Kf + k0);
    s8v tc = *(const s8v*)(bpH + k0);
    s8v td = *(const s8v*)(bpH + Kf + k0);
    __syncthreads();
    FragCvt u;
    u.v = ta;
    *(unsigned long long*)&Ahs[sb]     = u.q[0];
    *(unsigned long long*)&Ahs[sb + 4] = u.q[1];
    u.v = tb;
    *(unsigned long long*)&Als[sb]     = u.q[0];
    *(unsigned long long*)&Als[sb + 4] = u.q[1];
    u.v = tc;
    *(unsigned long long*)&Bhs[sb]     = u.q[0];
    *(unsigned long long*)&Bhs[sb + 4] = u.q[1];
    u.v = td;
    *(unsigned long long*)&Bls[sb]     = u.q[0];
    *(unsigned long long*)&Bls[sb + 4] = u.q[1];
    __syncthreads();
    s8v a0  = *(const s8v*)&Ahs[(wm * 32 + l16) * 40 + quad * 8];
    s8v a1  = *(const s8v*)&Ahs[(wm * 32 + 16 + l16) * 40 + quad * 8];
    s8v b0  = *(const s8v*)&Bhs[(wn * 32 + l16) * 40 + quad * 8];
    s8v b1  = *(const s8v*)&Bhs[(wn * 32 + 16 + l16) * 40 + quad * 8];
    s8v a0l = *(const s8v*)&Als[(wm * 32 + l16) * 40 + quad * 8];
    s8v a1l = *(const s8v*)&Als[(wm * 32 + 16 + l16) * 40 + quad * 8];
    s8v b0l = *(const s8v*)&Bls[(wn * 32 + l16) * 40 + quad * 8];
    s8v b1l = *(const s8v*)&Bls[(wn * 32 + 16 + l16) * 40 + quad * 8];
    acc[0][0] = mfma_b(a0, b0, acc[0][0]);
    acc[0][1] = mfma_b(a0, b1, acc[0][1]);
    acc[1][0] = mfma_b(a1, b0, acc[1][0]);
    acc[1][1] = mfma_b(a1, b1, acc[1][1]);
    acc[0][0] = mfma_b(a0, b0l, acc[0][0]);
    acc[0][1] = mfma_b(a0, b1l, acc[0][1]);
    acc[1][0] = mfma_b(a1, b0l, acc[1][0]);
    acc[1][1] = mfma_b(a1, b1l, acc[1][1]);
    acc[0][0] = mfma_b(a0l, b0, acc[0][0]);
    acc[0][1] = mfma_b(a0l, b1, acc[0][1]);
    acc[1][0] = mfma_b(a1l, b0, acc[1][0]);
    acc[1][1] = mfma_b(a1l, b1, acc[1][1]);
  }

  if (EP == 0) {
    #pragma unroll
    for (int i = 0; i < 2; ++i)
      #pragma unroll
      for (int j = 0; j < 2; ++j)
        #pragma unroll
        for (int r = 0; r < 4; ++r) {
          int mrow = m0 + wm * 32 + i * 16 + quad * 4 + r;
          int col = n0 + wn * 32 + j * 16 + l16;
          size_t idx = (size_t)mrow * N + col;
          C[idx] = acc[i][j][r] + (addend ? addend[idx] : 0.0f);
        }
  } else {
    if (n0 < 2048) {  // q region
      #pragma unroll
      for (int i = 0; i < 2; ++i)
        #pragma unroll
        for (int j = 0; j < 2; ++j)
          #pragma unroll
          for (int r = 0; r < 4; ++r) {
            int mrow = m0 + wm * 32 + i * 16 + quad * 4 + r;
            int col = n0 + wn * 32 + j * 16 + l16;
            C[(size_t)mrow * 2048 + col] = acc[i][j][r];
          }
    } else if (n0 < 2560) {  // k region
      #pragma unroll
      for (int i = 0; i < 2; ++i)
        #pragma unroll
        for (int j = 0; j < 2; ++j)
          #pragma unroll
          for (int r = 0; r < 4; ++r) {
            int mrow = m0 + wm * 32 + i * 16 + quad * 4 + r;
            int col = n0 + wn * 32 + j * 16 + l16 - 2048;
            kout[(size_t)mrow * 512 + col] = acc[i][j][r];
          }
    } else {  // v region: write transposed V^T [512][2048]
      #pragma unroll
      for (int i = 0; i < 2; ++i)
        #pragma unroll
        for (int j = 0; j < 2; ++j) {
          int vrow = n0 + wn * 32 + j * 16 + l16 - 2560;
          int mbase = m0 + wm * 32 + i * 16 + quad * 4;
          float4 vv;
          vv.x = acc[i][j][0]; vv.y = acc[i][j][1];
          vv.z = acc[i][j][2]; vv.w = acc[i][j][3];
          *(float4*)&vtout[(size_t)vrow * 2048 + mbase] = vv;
        }
    }
  }
}

// ---------------- per-head RMS + RoPE (in place) ----------------
__global__ __launch_bounds__(128) void qknorm_rope_kernel(
    float* __restrict__ X, const float* __restrict__ W,
    const int* __restrict__ positions, int ld) {
  __shared__ float wsum[2];
  __shared__ float xs[128];
  __shared__ float sc;
  int t = blockIdx.x, hh = blockIdx.y, d = threadIdx.x;
  float* row = X + (size_t)t * ld + hh * 128;
  float x = row[d];
  float ss = x * x;
  #pragma unroll
  for (int off = 32; off > 0; off >>= 1) ss += __shfl_down(ss, off);
  if ((d & 63) == 0) wsum[d >> 6] = ss;
  __syncthreads();
  if (d == 0) sc = rsqrtf((wsum[0] + wsum[1]) * (1.f / 128.f) + 1e-6f);
  __syncthreads();
  float xn = x * sc * (1.f + W[d]);
  xs[d] = xn;
  __syncthreads();
  int pos = positions[t];
  int i = d & 63;
  float invf = exp2f((float)i * (-19.931568569324174f / 64.f));
  float ang = (float)pos * invf;
  float cv = cosf(ang), sv = sinf(ang);
  float other = xs[d ^ 64];
  row[d] = (d < 64) ? (xn * cv - other * sv) : (xn * cv + other * sv);
}

// ---------------- MoE GEMM, 128x64 tile, bf16 A, XOR-swizzled B staging ----------------
// MODE 1: A = xnp hi (gathered entry>>1), B/B2 = w_gate/w_up (f32);
//         hout[slot][col] = bf16(silu(g)*u)
// MODE 2: A = hbuf bf16 (gathered slot), B = w_down (f32);
//         moeout[slot][col] = acc * gatebuf[slot]
// LDS chunk XOR: element (row, k) at [row*40 + ((k>>3)^((row>>3)&3))*8 + (k&7)]
template <int MODE>
__global__ __launch_bounds__(256) void gemm_moe(
    const u16b* __restrict__ Ap, int lda,
    const float* __restrict__ B, const float* __restrict__ B2,
    u16b* __restrict__ hout, float* __restrict__ moeout,
    const int* __restrict__ counts, const int* __restrict__ list,
    const float* __restrict__ gatebuf, int N, int K) {
  __shared__ __attribute__((aligned(16))) u16b As[128 * 40];
  __shared__ __attribute__((aligned(16))) u16b Bs[64 * 40];
  __shared__ __attribute__((aligned(16))) u16b B2s[(MODE == 1) ? 64 * 40 : 8];

  int n0 = blockIdx.x * 64;
  int m0 = blockIdx.y * 128;
  int e = blockIdx.z;
  int cnt = counts[e];
  if (m0 >= cnt) return;
  list += e * T_TOK;
  B += (size_t)e * K * N;
  if (MODE == 1) B2 += (size_t)e * K * N;

  int tid = threadIdx.x;
  int wave = tid >> 6, lane = tid & 63;
  int wm = wave >> 1, wn = wave & 1;
  int l16 = lane & 15, quad = lane >> 4;

  // A staging: row ar (0..127), two 16B chunks at chunk idx ac0, ac0+1
  int ar = tid >> 1, ac0 = (tid & 1) * 2;
  int axr = (ar >> 3) & 3;
  const u16b* aptr;
  {
    int mr = m0 + ar;
    if (mr > cnt - 1) mr = cnt - 1;
    int entry = list[mr];
    int arow = (MODE == 1) ? (entry >> 1) : entry;
    aptr = Ap + (size_t)arow * lda;
  }
  // B staging: k-row bk (0..31), 8 n at bn8
  int bk = tid >> 3, bn8 = (tid & 7) * 8;
  const float* bptr = B + (size_t)bk * N + n0 + bn8;
  const float* b2ptr = nullptr;
  if (MODE == 1) b2ptr = B2 + (size_t)bk * N + n0 + bn8;
  int bcol = (bk >> 3) * 8 + (bk & 7);  // chunk base before XOR (chunk = bk>>3)

  f4v acc[4][2];
  f4v acc2[4][2];
  #pragma unroll
  for (int i = 0; i < 4; ++i)
    #pragma unroll
    for (int j = 0; j < 2; ++j) { acc[i][j] = (f4v)0.0f; acc2[i][j] = (f4v)0.0f; }

  for (int k0 = 0; k0 < K; k0 += 32) {
    // issue global loads
    s8v ta0 = *(const s8v*)(aptr + k0 + ac0 * 8);
    s8v ta1 = *(const s8v*)(aptr + k0 + ac0 * 8 + 8);
    float4 g0 = *(const float4*)(bptr + (size_t)k0 * N);
    float4 g1 = *(const float4*)(bptr + (size_t)k0 * N + 4);
    float4 h0, h1;
    if (MODE == 1) {
      h0 = *(const float4*)(b2ptr + (size_t)k0 * N);
      h1 = *(const float4*)(b2ptr + (size_t)k0 * N + 4);
    }
    __syncthreads();
    // A: two 16B chunk stores with XOR
    *(s8v*)&As[ar * 40 + ((ac0 ^ axr) * 8)]       = ta0;
    *(s8v*)&As[ar * 40 + (((ac0 + 1) ^ axr) * 8)] = ta1;
    // B: transpose scatter with XOR on k-chunk
    {
      float f[8] = {g0.x, g0.y, g0.z, g0.w, g1.x, g1.y, g1.z, g1.w};
      #pragma unroll
      for (int x = 0; x < 8; ++x) {
        int n = bn8 + x;
        int col = ((bk >> 3) ^ ((n >> 3) & 3)) * 8 + (bk & 7);
        Bs[n * 40 + col] = f2bf(f[x]);
      }
      if (MODE == 1) {
        float f2[8] = {h0.x, h0.y, h0.z, h0.w, h1.x, h1.y, h1.z, h1.w};
        #pragma unroll
        for (int x = 0; x < 8; ++x) {
          int n = bn8 + x;
          int col = ((bk >> 3) ^ ((n >> 3) & 3)) * 8 + (bk & 7);
          B2s[n * 40 + col] = f2bf(f2[x]);
        }
      }
    }
    __syncthreads();
    // fragment reads (XOR-matched) + MFMA
    s8v a[4], b[2], c2[2];
    #pragma unroll
    for (int i = 0; i < 4; ++i) {
      int row = wm * 64 + i * 16 + l16;
      a[i] = *(const s8v*)&As[row * 40 + ((quad ^ ((row >> 3) & 3)) * 8)];
    }
    #pragma unroll
    for (int j = 0; j < 2; ++j) {
      int row = wn * 32 + j * 16 + l16;
      b[j] = *(const s8v*)&Bs[row * 40 + ((quad ^ ((row >> 3) & 3)) * 8)];
      if (MODE == 1)
        c2[j] = *(const s8v*)&B2s[row * 40 + ((quad ^ ((row >> 3) & 3)) * 8)];
    }
    __builtin_amdgcn_s_setprio(1);
    #pragma unroll
    for (int i = 0; i < 4; ++i)
      #pragma unroll
      for (int j = 0; j < 2; ++j) {
        acc[i][j] = mfma_b(a[i], b[j], acc[i][j]);
        if (MODE == 1) acc2[i][j] = mfma_b(a[i], c2[j], acc2[i][j]);
      }
    __builtin_amdgcn_s_setprio(0);
  }

  #pragma unroll
  for (int i = 0; i < 4; ++i)
    #pragma unroll
    for (int j = 0; j < 2; ++j)
      #pragma unroll
      for (int r = 0; r < 4; ++r) {
        int mrow = m0 + wm * 64 + i * 16 + quad * 4 + r;
        if (mrow < cnt) {
          int slot = list[mrow];
          int col = n0 + wn * 32 + j * 16 + l16;
          if (MODE == 1) {
            float g = acc[i][j][r], u = acc2[i][j][r];
            float hv = g / (1.0f + __expf(-g)) * u;  // silu(g)*u
            hout[(size_t)slot * N + col] = f2bf(hv);
          } else {
            moeout[(size_t)slot * N + col] = acc[i][j][r] * gatebuf[slot];
          }
        }
      }
}

// ---------------- flash attention: split-bf16 MFMA, 32x32 tiles ----------------
__global__ __launch_bounds__(256) void flash_kernel(
    const float* __restrict__ Q, const float* __restrict__ Kb,
    const float* __restrict__ VbT, u16b* __restrict__ attnp) {
  __shared__ __attribute__((aligned(16))) u16b Khi[32 * 136];
  __shared__ __attribute__((aligned(16))) u16b Klo[32 * 136];
  __shared__ __attribute__((aligned(16))) u16b Vthi[128 * 40];
  __shared__ __attribute__((aligned(16))) u16b Vtlo[128 * 40];
  __shared__ float Ss[32 * 36];
  __shared__ __attribute__((aligned(16))) u16b Phi[32 * 40];
  __shared__ __attribute__((aligned(16))) u16b Plo[32 * 40];
  __shared__ float red[32 * 8];
  __shared__ float mrow[32], lrow[32], arow[32];

  int qt = (gridDim.x - 1) - blockIdx.x;  // big tiles first
  int h = blockIdx.y;
  int g = h >> 2;  // GQA: 4 q-heads per kv-head
  int tid = threadIdx.x;
  int wave = tid >> 6, lane = tid & 63;
  int l16 = lane & 15, quad = lane >> 4;
  int sm = wave >> 1, sn = wave & 1;

  s8v qhi[4], qlo[4];
  {
    const float* qp = Q + (size_t)(qt * 32 + sm * 16 + l16) * 2048 + h * 128 + quad * 8;
    #pragma unroll
    for (int kc = 0; kc < 4; ++kc) {
      float4 f0 = *(const float4*)(qp + kc * 32);
      float4 f1 = *(const float4*)(qp + kc * 32 + 4);
      float f[8] = {f0.x, f0.y, f0.z, f0.w, f1.x, f1.y, f1.z, f1.w};
      u16b hi[8], lo[8];
      #pragma unroll
      for (int x = 0; x < 8; ++x) split2(f[x], hi[x], lo[x]);
      FragCvt ch, cl;
      ch.q[0] = pack4(hi); ch.q[1] = pack4(hi + 4);
      cl.q[0] = pack4(lo); cl.q[1] = pack4(lo + 4);
      qhi[kc] = ch.v; qlo[kc] = cl.v;
    }
  }

  if (tid < 32) { mrow[tid] = -1e30f; lrow[tid] = 0.f; }

  f4v o[4];
  #pragma unroll
  for (int db = 0; db < 4; ++db) o[db] = (f4v)0.0f;

  int krow = tid >> 3, ksk = (tid & 7) * 16;
  int vd = tid >> 1, vk0 = (tid & 1) * 16;
  int sr = tid >> 3, sp = tid & 7;

  const u16b* krow_h = &Khi[(sn * 16 + l16) * 136];
  const u16b* krow_l = &Klo[(sn * 16 + l16) * 136];

  for (int kt = 0; kt <= qt; ++kt) {
    __syncthreads();
    {
      const float* ks = Kb + (size_t)(kt * 32 + krow) * 512 + g * 128 + ksk;
      int kb = krow * 136 + ksk;
      #pragma unroll
      for (int half = 0; half < 2; ++half) {
        float4 f0 = *(const float4*)(ks + half * 8);
        float4 f1 = *(const float4*)(ks + half * 8 + 4);
        float f[8] = {f0.x, f0.y, f0.z, f0.w, f1.x, f1.y, f1.z, f1.w};
        u16b hi[8], lo[8];
        #pragma unroll
        for (int x = 0; x < 8; ++x) split2(f[x], hi[x], lo[x]);
        *(unsigned long long*)&Khi[kb + half * 8]     = pack4(hi);
        *(unsigned long long*)&Khi[kb + half * 8 + 4] = pack4(hi + 4);
        *(unsigned long long*)&Klo[kb + half * 8]     = pack4(lo);
        *(unsigned long long*)&Klo[kb + half * 8 + 4] = pack4(lo + 4);
      }
      const float* vs = VbT + (size_t)(g * 128 + vd) * 2048 + kt * 32 + vk0;
      int vb = vd * 40 + vk0;
      #pragma unroll
      for (int half = 0; half < 2; ++half) {
        float4 f0 = *(const float4*)(vs + half * 8);
        float4 f1 = *(const float4*)(vs + half * 8 + 4);
        float f[8] = {f0.x, f0.y, f0.z, f0.w, f1.x, f1.y, f1.z, f1.w};
        u16b hi[8], lo[8];
        #pragma unroll
        for (int x = 0; x < 8; ++x) split2(f[x], hi[x], lo[x]);
        *(unsigned long long*)&Vthi[vb + half * 8]     = pack4(hi);
        *(unsigned long long*)&Vthi[vb + half * 8 + 4] = pack4(hi + 4);
        *(unsigned long long*)&Vtlo[vb + half * 8]     = pack4(lo);
        *(unsigned long long*)&Vtlo[vb + half * 8 + 4] = pack4(lo + 4);
      }
    }
    __syncthreads();
    f4v a0 = (f4v)0.0f, a1 = (f4v)0.0f, a2 = (f4v)0.0f;
    __builtin_amdgcn_s_setprio(1);
    #pragma unroll
    for (int kc = 0; kc < 4; ++kc) {
      s8v kh = *(const s8v*)(krow_h + kc * 32 + quad * 8);
      s8v kl = *(const s8v*)(krow_l + kc * 32 + quad * 8);
      a0 = mfma_b(qhi[kc], kh, a0);
      a1 = mfma_b(qhi[kc], kl, a1);
      a2 = mfma_b(qlo[kc], kh, a2);
    }
    __builtin_amdgcn_s_setprio(0);
    {
      f4v sacc = a0 + a1 + a2;
      const float sc = 0.08838834764831845f;  // 1/sqrt(128)
      #pragma unroll
      for (int r = 0; r < 4; ++r) {
        int row_l = sm * 16 + quad * 4 + r;
        int col_l = sn * 16 + l16;
        int qb = qt * 32 + row_l, kb2 = kt * 32 + col_l;
        Ss[row_l * 36 + col_l] = (kb2 <= qb) ? sacc[r] * sc : -1e30f;
      }
    }
    __syncthreads();
    float mx = -3e38f;
    #pragma unroll
    for (int c = sp * 4; c < sp * 4 + 4; ++c) mx = fmaxf(mx, Ss[sr * 36 + c]);
    red[sr * 8 + sp] = mx;
    __syncthreads();
    if (sp == 0) {
      float mn = mrow[sr];
      #pragma unroll
      for (int p = 0; p < 8; ++p) mn = fmaxf(mn, red[sr * 8 + p]);
      arow[sr] = __expf(mrow[sr] - mn);
      mrow[sr] = mn;
    }
    __syncthreads();
    {
      float m = mrow[sr];
      float sum = 0.f;
      #pragma unroll
      for (int c = sp * 4; c < sp * 4 + 4; ++c) {
        float e2 = __expf(Ss[sr * 36 + c] - m);
        u16b eh, el;
        split2(e2, eh, el);
        Phi[sr * 40 + c] = eh;
        Plo[sr * 40 + c] = el;
        sum += e2;
      }
      red[sr * 8 + sp] = sum;
    }
    __syncthreads();
    if (sp == 0) {
      float s2 = 0.f;
      #pragma unroll
      for (int p = 0; p < 8; ++p) s2 += red[sr * 8 + p];
      lrow[sr] = lrow[sr] * arow[sr] + s2;
    }
    {
      f4v arv;
      arv[0] = arow[sm * 16 + quad * 4 + 0];
      arv[1] = arow[sm * 16 + quad * 4 + 1];
      arv[2] = arow[sm * 16 + quad * 4 + 2];
      arv[3] = arow[sm * 16 + quad * 4 + 3];
      #pragma unroll
      for (int db = 0; db < 4; ++db) o[db] *= arv;

      s8v pah = *(const s8v*)&Phi[(sm * 16 + l16) * 40 + quad * 8];
      s8v pal = *(const s8v*)&Plo[(sm * 16 + l16) * 40 + quad * 8];
      __builtin_amdgcn_s_setprio(1);
      #pragma unroll
      for (int db = 0; db < 4; ++db) {
        int vrow = sn * 64 + db * 16 + l16;
        s8v vh = *(const s8v*)&Vthi[vrow * 40 + quad * 8];
        s8v vl = *(const s8v*)&Vtlo[vrow * 40 + quad * 8];
        o[db] = mfma_b(pah, vh, o[db]);
        o[db] = mfma_b(pah, vl, o[db]);
        o[db] = mfma_b(pal, vh, o[db]);
      }
      __builtin_amdgcn_s_setprio(0);
    }
  }
  __syncthreads();
  {
    int row0 = sm * 16 + quad * 4;
    f4v invv;
    invv[0] = 1.f / lrow[row0 + 0];
    invv[1] = 1.f / lrow[row0 + 1];
    invv[2] = 1.f / lrow[row0 + 2];
    invv[3] = 1.f / lrow[row0 + 3];
    #pragma unroll
    for (int db = 0; db < 4; ++db) o[db] *= invv;
    #pragma unroll
    for (int r = 0; r < 4; ++r) {
      u16b* ob = attnp + (size_t)(qt * 32 + row0 + r) * 4096 + h * 128 + sn * 64 + l16;
      #pragma unroll
      for (int db = 0; db < 4; ++db) {
        u16b hh, ll;
        split2(o[db][r], hh, ll);
        ob[db * 16] = hh;
        ob[2048 + db * 16] = ll;
      }
    }
  }
}

// ---------------- router ----------------
__global__ __launch_bounds__(256) void router_kernel(
    const float* __restrict__ xn2, const float* __restrict__ rw,
    int* __restrict__ counts, int* __restrict__ list, float* __restrict__ gatebuf) {
  __shared__ float red[256];
  __shared__ float logits[16];
  int t = blockIdx.x, tid = threadIdx.x;
  int e = tid >> 4, p = tid & 15;
  const float* xr = xn2 + (size_t)t * HID;
  float s = 0.f;
  for (int j = p * 128; j < p * 128 + 128; ++j) s += xr[j] * rw[j * 16 + e];
  red[tid] = s;
  __syncthreads();
  if (tid < 16) {
    float l = 0.f;
    #pragma unroll
    for (int p2 = 0; p2 < 16; ++p2) l += red[tid * 16 + p2];
    logits[tid] = l;
  }
  __syncthreads();
  if (tid == 0) {
    int i0 = 0; float l0 = logits[0];
    for (int i = 1; i < 16; ++i) if (logits[i] > l0) { l0 = logits[i]; i0 = i; }
    int i1 = -1; float l1 = -3e38f;
    for (int i = 0; i < 16; ++i) if (i != i0 && logits[i] > l1) { l1 = logits[i]; i1 = i; }
    float g0 = 1.f / (1.f + __expf(l1 - l0));
    float g1 = 1.f - g0;
    int s0 = atomicAdd(&counts[i0], 1);
    list[i0 * T_TOK + s0] = t * 2;
    gatebuf[t * 2] = g0;
    int s1 = atomicAdd(&counts[i1], 1);
    list[i1 * T_TOK + s1] = t * 2 + 1;
    gatebuf[t * 2 + 1] = g1;
  }
}

// ---------------- final ----------------
__global__ __launch_bounds__(256) void final_kernel(
    const float* __restrict__ moeout, const float* __restrict__ resid,
    const float* __restrict__ W, float* __restrict__ out) {
  __shared__ float lds[4];
  int t = blockIdx.x, tid = threadIdx.x;
  const float* m0 = moeout + (size_t)(2 * t) * HID;
  const float* m1 = moeout + (size_t)(2 * t + 1) * HID;
  const float* rr = resid + (size_t)t * HID;
  float v[8]; float ss = 0.f;
  #pragma unroll
  for (int i = 0; i < 8; ++i) {
    int j = tid + i * 256;
    v[i] = m0[j] + m1[j] + rr[j];
    ss += v[i] * v[i];
  }
  float tot = blk_sum_256(ss, lds);
  float scale = rsqrtf(tot * (1.f / (float)HID) + 1e-6f);
  float* orow = out + (size_t)t * HID;
  #pragma unroll
  for (int i = 0; i < 8; ++i) {
    int j = tid + i * 256;
    orow[j] = v[i] * scale * (1.f + W[j]);
  }
}

extern "C" void kernel_launch(void* const* d_in, const int* in_sizes, int n_in,
                              void* d_out, int out_size, void* d_ws, size_t ws_size,
                              hipStream_t stream) {
  const int* input_ids   = (const int*)d_in[0];
  const int* positions   = (const int*)d_in[1];
  const float* hidden    = (const float*)d_in[2];
  const float* embed_w   = (const float*)d_in[4];
  const float* fc_w      = (const float*)d_in[5];
  const float* pre_emb   = (const float*)d_in[6];
  const float* pre_hid   = (const float*)d_in[7];
  const float* in_ln     = (const float*)d_in[8];
  const float* post_ln   = (const float*)d_in[9];
  const float* final_w   = (const float*)d_in[10];
  const float* wq        = (const float*)d_in[11];
  const float* wk        = (const float*)d_in[12];
  const float* wv        = (const float*)d_in[13];
  const float* wo        = (const float*)d_in[14];
  const float* qnw       = (const float*)d_in[15];
  const float* knw       = (const float*)d_in[16];
  const float* rw        = (const float*)d_in[17];
  const float* wg        = (const float*)d_in[18];
  const float* wu        = (const float*)d_in[19];
  const float* wd        = (const float*)d_in[20];

  char* ws = (char*)d_ws;
  u16b*  catp   = (u16b*)(ws + 0);            // 2048 x 8192 bf16 = 32 MB
  u16b*  qkvw   = (u16b*)(ws + 0);            // 3072 x 4096 bf16 = 24 MB
  float* moeout = (float*)(ws + 0);           // 4096 x 2048 f32 = 32 MB
  float* x      = (float*)(ws + 33554432);    // 16 MB fc out / residual1
  u16b*  xnp    = (u16b*)(ws + 50331648);     // 2048 x 4096 bf16 = 16 MB
  u16b*  wotw   = (u16b*)(ws + 50331648);     // 2048 x 4096 bf16 = 16 MB
  float* q      = (float*)(ws + 67108864);    // 16 MB
  u16b*  hbuf16 = (u16b*)(ws + 67108864);     // 4096 x 1024 bf16 = 8 MB (q dead)
  float* kbuf   = (float*)(ws + 83886080);    // 4 MB
  float* vbufT  = (float*)(ws + 88080384);    // 4 MB (V^T: 512 x 2048 f32)
  u16b*  fctw   = (u16b*)(ws + 92274688);     // 2048 x 8192 bf16 = 32 MB
  u16b*  attnp  = (u16b*)(ws + 92274688);     // 2048 x 4096 bf16 = 16 MB
  float* x2     = (float*)(ws + 109051904);   // 16 MB residual2
  float* xn2    = (float*)(ws + 125829120);   // 16 MB
  int*   counts = (int*)(ws + 142606336);     // 64 B
  int*   list   = (int*)(ws + 142606592);     // 128 KB
  float* gateb  = (float*)(ws + 142737664);   // 16 KB

  zero_counts_kernel<<<1, 64, 0, stream>>>(counts);
  embed_cat_kernel<<<dim3(2048, 2), 256, 0, stream>>>(input_ids, embed_w, hidden,
                                                      pre_emb, pre_hid, catp);
  tsplit_kernel<<<dim3(32, 64), 256, 0, stream>>>(fc_w, fctw, 4096, 2048, 0);
  gemm_bs<0><<<dim3(32, 32), 256, 0, stream>>>(catp, fctw, x, nullptr,
                                               nullptr, nullptr, 2048, 2048, 4096);
  tsplit_kernel<<<dim3(32, 32), 256, 0, stream>>>(wq, qkvw, 2048, 2048, 0);
  tsplit_kernel<<<dim3(8, 32), 256, 0, stream>>>(wk, qkvw, 2048, 512, 2048);
  tsplit_kernel<<<dim3(8, 32), 256, 0, stream>>>(wv, qkvw, 2048, 512, 2560);
  rms_split_kernel<<<2048, 256, 0, stream>>>(x, in_ln, xnp);
  gemm_bs<1><<<dim3(48, 32), 256, 0, stream>>>(xnp, qkvw, q, nullptr,
                                               kbuf, vbufT, 2048, 3072, 2048);
  tsplit_kernel<<<dim3(32, 32), 256, 0, stream>>>(wo, wotw, 2048, 2048, 0);
  qknorm_rope_kernel<<<dim3(2048, 16), 128, 0, stream>>>(q, qnw, positions, 2048);
  qknorm_rope_kernel<<<dim3(2048, 4), 128, 0, stream>>>(kbuf, knw, positions, 512);
  flash_kernel<<<dim3(64, 16), 256, 0, stream>>>(q, kbuf, vbufT, attnp);
  gemm_bs<0><<<dim3(32, 32), 256, 0, stream>>>(attnp, wotw, x2, x,
                                               nullptr, nullptr, 2048, 2048, 2048);
  rms_f32_kernel<<<2048, 256, 0, stream>>>(x2, post_ln, xn2);
  rms_split_kernel<<<2048, 256, 0, stream>>>(x2, post_ln, xnp);
  router_kernel<<<2048, 256, 0, stream>>>(xn2, rw, counts, list, gateb);
  gemm_moe<1><<<dim3(16, 16, 16), 256, 0, stream>>>(xnp, 4096, wg, wu, hbuf16,
                                                    nullptr, counts, list, nullptr,
                                                    1024, 2048);
  gemm_moe<2><<<dim3(32, 16, 16), 256, 0, stream>>>(hbuf16, 1024, wd, nullptr, nullptr,
                                                    moeout, counts, list, gateb,
                                                    2048, 1024);
  final_kernel<<<2048, 256, 0, stream>>>(moeout, x2, final_w, (float*)d_out);
}

// Round 5
// 1482.121 us; speedup vs baseline: 1.9285x; 1.0398x over previous
//
#include <hip/hip_runtime.h>
#include <cstddef>

// Qwen3.5 MTP layer, MI355X gfx950. Round 6: pre-split K/V for flash; 128x64 dense tiles.
// T=2048 H=2048 V=32000 NH=16 NKV=4 DH=128 E=16 K=2 I=1024
// Dense GEMMs (fc, qkv, wo): pre-split bf16 A x pre-transposed split bf16 B,
// 3-term hi/lo, 128x64 tiles, 24 MFMA per k-step. Flash: split-bf16 MFMA with
// K/V pre-split by producers (rope kernel / qkv epilogue) -> staging is pure copies.
// MoE: single bf16, 128x64 tiles, XOR-swizzled B staging (unchanged from round 5).

typedef unsigned short u16b;
typedef __attribute__((ext_vector_type(8))) short s8v;   // 8 x bf16 frag
typedef __attribute__((ext_vector_type(4))) float f4v;   // MFMA acc

#define T_TOK 2048
#define HID   2048

__device__ __forceinline__ float bf2f(u16b h) {
  return __uint_as_float(((unsigned int)h) << 16);
}
__device__ __forceinline__ u16b f2bf(float f) {
  unsigned int u = __float_as_uint(f);
  return (u16b)((u + 0x7fffu + ((u >> 16) & 1u)) >> 16);
}
__device__ __forceinline__ void split2(float f, u16b& hi, u16b& lo) {
  hi = f2bf(f);
  lo = f2bf(f - bf2f(hi));
}
__device__ __forceinline__ unsigned long long pack4(const u16b* p) {
  return (unsigned long long)p[0] | ((unsigned long long)p[1] << 16) |
         ((unsigned long long)p[2] << 32) | ((unsigned long long)p[3] << 48);
}
__device__ __forceinline__ f4v mfma_b(s8v a, s8v b, f4v c) {
  return __builtin_amdgcn_mfma_f32_16x16x32_bf16(a, b, c, 0, 0, 0);
}
union FragCvt { unsigned long long q[2]; s8v v; };

// block=256 sum-reduce
__device__ __forceinline__ float blk_sum_256(float v, float* lds4) {
  #pragma unroll
  for (int off = 32; off > 0; off >>= 1) v += __shfl_down(v, off);
  int tid = threadIdx.x;
  if ((tid & 63) == 0) lds4[tid >> 6] = v;
  __syncthreads();
  return lds4[0] + lds4[1] + lds4[2] + lds4[3];
}

// ---------------- zero counts ----------------
__global__ void zero_counts_kernel(int* counts) {
  if (threadIdx.x < 16) counts[threadIdx.x] = 0;
}

// ---------------- embed gather + RMS + concat -> split bf16 A' ----------------
__global__ __launch_bounds__(256) void embed_cat_kernel(
    const int* __restrict__ ids, const float* __restrict__ embw,
    const float* __restrict__ hid, const float* __restrict__ w_emb,
    const float* __restrict__ w_hid, u16b* __restrict__ catp) {
  __shared__ float lds[4];
  int t = blockIdx.x, which = blockIdx.y, tid = threadIdx.x;
  const float* src;
  const float* w;
  if (which == 0) { src = embw + (size_t)ids[t] * HID; w = w_emb; }
  else            { src = hid  + (size_t)t * HID;      w = w_hid; }
  u16b* dst = catp + (size_t)t * 8192 + which * 2048;
  float v[8]; float ss = 0.f;
  #pragma unroll
  for (int i = 0; i < 8; ++i) { v[i] = src[tid + i * 256]; ss += v[i] * v[i]; }
  float tot = blk_sum_256(ss, lds);
  float scale = rsqrtf(tot * (1.f / (float)HID) + 1e-6f);
  #pragma unroll
  for (int i = 0; i < 8; ++i) {
    int j = tid + i * 256;
    float val = v[i] * scale * (1.f + w[j]);
    u16b h, l;
    split2(val, h, l);
    dst[j] = h;
    dst[4096 + j] = l;
  }
}

// ---------------- RMS norm on f32 rows -> f32 out ----------------
__global__ __launch_bounds__(256) void rms_f32_kernel(
    const float* __restrict__ X, const float* __restrict__ W, float* __restrict__ Y) {
  __shared__ float lds[4];
  int t = blockIdx.x, tid = threadIdx.x;
  const float* row = X + (size_t)t * HID;
  float v[8]; float ss = 0.f;
  #pragma unroll
  for (int i = 0; i < 8; ++i) { v[i] = row[tid + i * 256]; ss += v[i] * v[i]; }
  float tot = blk_sum_256(ss, lds);
  float scale = rsqrtf(tot * (1.f / (float)HID) + 1e-6f);
  float* yrow = Y + (size_t)t * HID;
  #pragma unroll
  for (int i = 0; i < 8; ++i) {
    int j = tid + i * 256;
    yrow[j] = v[i] * scale * (1.f + W[j]);
  }
}

// ---------------- RMS norm -> split bf16 A' [hi|lo], ld 2*HID ----------------
__global__ __launch_bounds__(256) void rms_split_kernel(
    const float* __restrict__ X, const float* __restrict__ W, u16b* __restrict__ Yp) {
  __shared__ float lds[4];
  int t = blockIdx.x, tid = threadIdx.x;
  const float* row = X + (size_t)t * HID;
  float v[8]; float ss = 0.f;
  #pragma unroll
  for (int i = 0; i < 8; ++i) { v[i] = row[tid + i * 256]; ss += v[i] * v[i]; }
  float tot = blk_sum_256(ss, lds);
  float scale = rsqrtf(tot * (1.f / (float)HID) + 1e-6f);
  u16b* yrow = Yp + (size_t)t * (2 * HID);
  #pragma unroll
  for (int i = 0; i < 8; ++i) {
    int j = tid + i * 256;
    float val = v[i] * scale * (1.f + W[j]);
    u16b h, l;
    split2(val, h, l);
    yrow[j] = h;
    yrow[HID + j] = l;
  }
}

// ---------------- weight transpose + split: B f32 [K][N] -> Bt bf16 [N][2K] ----------------
__global__ __launch_bounds__(256) void tsplit_kernel(
    const float* __restrict__ B, u16b* __restrict__ Bt,
    int Kf, int N, int row_off) {
  __shared__ u16b ht[64][68];
  __shared__ u16b lt[64][68];
  int n0 = blockIdx.x * 64, k0 = blockIdx.y * 64;
  int tid = threadIdx.x;
  int kl = tid >> 4, nl = (tid & 15) * 4;
  #pragma unroll
  for (int p = 0; p < 4; ++p) {
    int kk = p * 16 + kl;
    float4 f = *(const float4*)&B[(size_t)(k0 + kk) * N + n0 + nl];
    float ff[4] = {f.x, f.y, f.z, f.w};
    #pragma unroll
    for (int j = 0; j < 4; ++j) {
      u16b h, l;
      split2(ff[j], h, l);
      ht[nl + j][kk] = h;
      lt[nl + j][kk] = l;
    }
  }
  __syncthreads();
  int ldo = 2 * Kf;
  int nr = tid >> 2, kc = (tid & 3) * 16;
  u16b* orow = Bt + (size_t)(row_off + n0 + nr) * ldo + k0 + kc;
  #pragma unroll
  for (int c = 0; c < 4; ++c) {
    *(unsigned long long*)(orow + c * 4)      = *(const unsigned long long*)&ht[nr][kc + c * 4];
    *(unsigned long long*)(orow + Kf + c * 4) = *(const unsigned long long*)&lt[nr][kc + c * 4];
  }
}

// ---------------- dense split-bf16 GEMM, 128x64 tiles ----------------
// A' [M][2Kf] bf16 [hi|lo]; Bt [N][2Kf] bf16 [hi|lo] (pre-transposed weights).
// 4 waves as 2m x 2n; per wave 4x2 16x16 frags; 24 MFMA per 32-k step (hh+hl+lh).
// EP 0: C[m][n] = acc (+addend). EP 1: qkv scatter (q f32 / k f32 / V^T split bf16).
template <int EP>
__global__ __launch_bounds__(256) void gemm_bs(
    const u16b* __restrict__ Ap, const u16b* __restrict__ Bp,
    float* __restrict__ C, const float* __restrict__ addend,
    float* __restrict__ kout, u16b* __restrict__ vtout,
    int M, int N, int Kf) {
  __shared__ __attribute__((aligned(16))) u16b Ahs[128 * 40];
  __shared__ __attribute__((aligned(16))) u16b Als[128 * 40];
  __shared__ __attribute__((aligned(16))) u16b Bhs[64 * 40];
  __shared__ __attribute__((aligned(16))) u16b Bls[64 * 40];
  int n0 = blockIdx.x * 64, m0 = blockIdx.y * 128;
  int tid = threadIdx.x;
  int wave = tid >> 6, lane = tid & 63;
  int wm = wave >> 1, wn = wave & 1;
  int l16 = lane & 15, quad = lane >> 4;
  int lda = 2 * Kf;
  int ar = tid >> 1, ac = (tid & 1) * 16;   // A stage: 128 rows x 32 k, 16 u16/thread
  int br = tid >> 2, bc = (tid & 3) * 8;    // B stage: 64 rows x 32 k, 8 u16/thread
  const u16b* apH = Ap + (size_t)(m0 + ar) * lda + ac;
  const u16b* bpH = Bp + (size_t)(n0 + br) * lda + bc;
  int sa = ar * 40 + ac;
  int sbb = br * 40 + bc;

  f4v acc[4][2];
  #pragma unroll
  for (int i = 0; i < 4; ++i)
    #pragma unroll
    for (int j = 0; j < 2; ++j) acc[i][j] = (f4v)0.0f;

  for (int k0 = 0; k0 < Kf; k0 += 32) {
    s8v ah0 = *(const s8v*)(apH + k0);
    s8v ah1 = *(const s8v*)(apH + k0 + 8);
    s8v al0 = *(const s8v*)(apH + Kf + k0);
    s8v al1 = *(const s8v*)(apH + Kf + k0 + 8);
    s8v bh  = *(const s8v*)(bpH + k0);
    s8v bl  = *(const s8v*)(bpH + Kf + k0);
    __syncthreads();
    *(s8v*)&Ahs[sa]     = ah0;
    *(s8v*)&Ahs[sa + 8] = ah1;
    *(s8v*)&Als[sa]     = al0;
    *(s8v*)&Als[sa + 8] = al1;
    *(s8v*)&Bhs[sbb] = bh;
    *(s8v*)&Bls[sbb] = bl;
    __syncthreads();
    s8v a[4], al[4], b[2], bl2[2];
    #pragma unroll
    for (int i = 0; i < 4; ++i) {
      int row = wm * 64 + i * 16 + l16;
      a[i]  = *(const s8v*)&Ahs[row * 40 + quad * 8];
      al[i] = *(const s8v*)&Als[row * 40 + quad * 8];
    }
    #pragma unroll
    for (int j = 0; j < 2; ++j) {
      int row = wn * 32 + j * 16 + l16;
      b[j]   = *(const s8v*)&Bhs[row * 40 + quad * 8];
      bl2[j] = *(const s8v*)&Bls[row * 40 + quad * 8];
    }
    __builtin_amdgcn_s_setprio(1);
    #pragma unroll
    for (int i = 0; i < 4; ++i)
      #pragma unroll
      for (int j = 0; j < 2; ++j) {
        acc[i][j] = mfma_b(a[i], b[j], acc[i][j]);
        acc[i][j] = mfma_b(a[i], bl2[j], acc[i][j]);
        acc[i][j] = mfma_b(al[i], b[j], acc[i][j]);
      }
    __builtin_amdgcn_s_setprio(0);
  }

  if (EP == 0) {
    #pragma unroll
    for (int i = 0; i < 4; ++i)
      #pragma unroll
      for (int j = 0; j < 2; ++j)
        #pragma unroll
        for (int r = 0; r < 4; ++r) {
          int mrow = m0 + wm * 64 + i * 16 + quad * 4 + r;
          int col = n0 + wn * 32 + j * 16 + l16;
          size_t idx = (size_t)mrow * N + col;
          C[idx] = acc[i][j][r] + (addend ? addend[idx] : 0.0f);
        }
  } else {
    if (n0 < 2048) {  // q region (f32)
      #pragma unroll
      for (int i = 0; i < 4; ++i)
        #pragma unroll
        for (int j = 0; j < 2; ++j)
          #pragma unroll
          for (int r = 0; r < 4; ++r) {
            int mrow = m0 + wm * 64 + i * 16 + quad * 4 + r;
            int col = n0 + wn * 32 + j * 16 + l16;
            C[(size_t)mrow * 2048 + col] = acc[i][j][r];
          }
    } else if (n0 < 2560) {  // k region (f32 raw, pre-norm/rope)
      #pragma unroll
      for (int i = 0; i < 4; ++i)
        #pragma unroll
        for (int j = 0; j < 2; ++j)
          #pragma unroll
          for (int r = 0; r < 4; ++r) {
            int mrow = m0 + wm * 64 + i * 16 + quad * 4 + r;
            int col = n0 + wn * 32 + j * 16 + l16 - 2048;
            kout[(size_t)mrow * 512 + col] = acc[i][j][r];
          }
    } else {  // v region: split bf16 V^T [512][4096]: [hi 2048 | lo 2048] per row
      #pragma unroll
      for (int i = 0; i < 4; ++i)
        #pragma unroll
        for (int j = 0; j < 2; ++j) {
          int vrow = n0 + wn * 32 + j * 16 + l16 - 2560;
          int mbase = m0 + wm * 64 + i * 16 + quad * 4;
          u16b hi4[4], lo4[4];
          #pragma unroll
          for (int r = 0; r < 4; ++r) split2(acc[i][j][r], hi4[r], lo4[r]);
          *(unsigned long long*)&vtout[(size_t)vrow * 4096 + mbase]        = pack4(hi4);
          *(unsigned long long*)&vtout[(size_t)vrow * 4096 + 2048 + mbase] = pack4(lo4);
        }
    }
  }
}

// ---------------- per-head RMS + RoPE for Q (in place, f32) ----------------
__global__ __launch_bounds__(128) void qknorm_rope_kernel(
    float* __restrict__ X, const float* __restrict__ W,
    const int* __restrict__ positions, int ld) {
  __shared__ float wsum[2];
  __shared__ float xs[128];
  __shared__ float sc;
  int t = blockIdx.x, hh = blockIdx.y, d = threadIdx.x;
  float* row = X + (size_t)t * ld + hh * 128;
  float x = row[d];
  float ss = x * x;
  #pragma unroll
  for (int off = 32; off > 0; off >>= 1) ss += __shfl_down(ss, off);
  if ((d & 63) == 0) wsum[d >> 6] = ss;
  __syncthreads();
  if (d == 0) sc = rsqrtf((wsum[0] + wsum[1]) * (1.f / 128.f) + 1e-6f);
  __syncthreads();
  float xn = x * sc * (1.f + W[d]);
  xs[d] = xn;
  __syncthreads();
  int pos = positions[t];
  int i = d & 63;
  float invf = exp2f((float)i * (-19.931568569324174f / 64.f));
  float ang = (float)pos * invf;
  float cv = cosf(ang), sv = sinf(ang);
  float other = xs[d ^ 64];
  row[d] = (d < 64) ? (xn * cv - other * sv) : (xn * cv + other * sv);
}

// ---------------- K: RMS + RoPE -> split bf16 kp [T][1024] ([hi 512 | lo 512]) ----------------
__global__ __launch_bounds__(128) void knorm_rope_split_kernel(
    const float* __restrict__ X, const float* __restrict__ W,
    const int* __restrict__ positions, u16b* __restrict__ Kp) {
  __shared__ float wsum[2];
  __shared__ float xs[128];
  __shared__ float sc;
  int t = blockIdx.x, hh = blockIdx.y, d = threadIdx.x;
  const float* row = X + (size_t)t * 512 + hh * 128;
  float x = row[d];
  float ss = x * x;
  #pragma unroll
  for (int off = 32; off > 0; off >>= 1) ss += __shfl_down(ss, off);
  if ((d & 63) == 0) wsum[d >> 6] = ss;
  __syncthreads();
  if (d == 0) sc = rsqrtf((wsum[0] + wsum[1]) * (1.f / 128.f) + 1e-6f);
  __syncthreads();
  float xn = x * sc * (1.f + W[d]);
  xs[d] = xn;
  __syncthreads();
  int pos = positions[t];
  int i = d & 63;
  float invf = exp2f((float)i * (-19.931568569324174f / 64.f));
  float ang = (float)pos * invf;
  float cv = cosf(ang), sv = sinf(ang);
  float other = xs[d ^ 64];
  float val = (d < 64) ? (xn * cv - other * sv) : (xn * cv + other * sv);
  u16b h, l;
  split2(val, h, l);
  Kp[(size_t)t * 1024 + hh * 128 + d] = h;
  Kp[(size_t)t * 1024 + 512 + hh * 128 + d] = l;
}

// ---------------- MoE GEMM, 128x64 tile, bf16 A, XOR-swizzled B staging ----------------
template <int MODE>
__global__ __launch_bounds__(256) void gemm_moe(
    const u16b* __restrict__ Ap, int lda,
    const float* __restrict__ B, const float* __restrict__ B2,
    u16b* __restrict__ hout, float* __restrict__ moeout,
    const int* __restrict__ counts, const int* __restrict__ list,
    const float* __restrict__ gatebuf, int N, int K) {
  __shared__ __attribute__((aligned(16))) u16b As[128 * 40];
  __shared__ __attribute__((aligned(16))) u16b Bs[64 * 40];
  __shared__ __attribute__((aligned(16))) u16b B2s[(MODE == 1) ? 64 * 40 : 8];

  int n0 = blockIdx.x * 64;
  int m0 = blockIdx.y * 128;
  int e = blockIdx.z;
  int cnt = counts[e];
  if (m0 >= cnt) return;
  list += e * T_TOK;
  B += (size_t)e * K * N;
  if (MODE == 1) B2 += (size_t)e * K * N;

  int tid = threadIdx.x;
  int wave = tid >> 6, lane = tid & 63;
  int wm = wave >> 1, wn = wave & 1;
  int l16 = lane & 15, quad = lane >> 4;

  int ar = tid >> 1, ac0 = (tid & 1) * 2;
  int axr = (ar >> 3) & 3;
  const u16b* aptr;
  {
    int mr = m0 + ar;
    if (mr > cnt - 1) mr = cnt - 1;
    int entry = list[mr];
    int arow = (MODE == 1) ? (entry >> 1) : entry;
    aptr = Ap + (size_t)arow * lda;
  }
  int bk = tid >> 3, bn8 = (tid & 7) * 8;
  const float* bptr = B + (size_t)bk * N + n0 + bn8;
  const float* b2ptr = nullptr;
  if (MODE == 1) b2ptr = B2 + (size_t)bk * N + n0 + bn8;

  f4v acc[4][2];
  f4v acc2[4][2];
  #pragma unroll
  for (int i = 0; i < 4; ++i)
    #pragma unroll
    for (int j = 0; j < 2; ++j) { acc[i][j] = (f4v)0.0f; acc2[i][j] = (f4v)0.0f; }

  for (int k0 = 0; k0 < K; k0 += 32) {
    s8v ta0 = *(const s8v*)(aptr + k0 + ac0 * 8);
    s8v ta1 = *(const s8v*)(aptr + k0 + ac0 * 8 + 8);
    float4 g0 = *(const float4*)(bptr + (size_t)k0 * N);
    float4 g1 = *(const float4*)(bptr + (size_t)k0 * N + 4);
    float4 h0, h1;
    if (MODE == 1) {
      h0 = *(const float4*)(b2ptr + (size_t)k0 * N);
      h1 = *(const float4*)(b2ptr + (size_t)k0 * N + 4);
    }
    __syncthreads();
    *(s8v*)&As[ar * 40 + ((ac0 ^ axr) * 8)]       = ta0;
    *(s8v*)&As[ar * 40 + (((ac0 + 1) ^ axr) * 8)] = ta1;
    {
      float f[8] = {g0.x, g0.y, g0.z, g0.w, g1.x, g1.y, g1.z, g1.w};
      #pragma unroll
      for (int x = 0; x < 8; ++x) {
        int n = bn8 + x;
        int col = ((bk >> 3) ^ ((n >> 3) & 3)) * 8 + (bk & 7);
        Bs[n * 40 + col] = f2bf(f[x]);
      }
      if (MODE == 1) {
        float f2[8] = {h0.x, h0.y, h0.z, h0.w, h1.x, h1.y, h1.z, h1.w};
        #pragma unroll
        for (int x = 0; x < 8; ++x) {
          int n = bn8 + x;
          int col = ((bk >> 3) ^ ((n >> 3) & 3)) * 8 + (bk & 7);
          B2s[n * 40 + col] = f2bf(f2[x]);
        }
      }
    }
    __syncthreads();
    s8v a[4], b[2], c2[2];
    #pragma unroll
    for (int i = 0; i < 4; ++i) {
      int row = wm * 64 + i * 16 + l16;
      a[i] = *(const s8v*)&As[row * 40 + ((quad ^ ((row >> 3) & 3)) * 8)];
    }
    #pragma unroll
    for (int j = 0; j < 2; ++j) {
      int row = wn * 32 + j * 16 + l16;
      b[j] = *(const s8v*)&Bs[row * 40 + ((quad ^ ((row >> 3) & 3)) * 8)];
      if (MODE == 1)
        c2[j] = *(const s8v*)&B2s[row * 40 + ((quad ^ ((row >> 3) & 3)) * 8)];
    }
    __builtin_amdgcn_s_setprio(1);
    #pragma unroll
    for (int i = 0; i < 4; ++i)
      #pragma unroll
      for (int j = 0; j < 2; ++j) {
        acc[i][j] = mfma_b(a[i], b[j], acc[i][j]);
        if (MODE == 1) acc2[i][j] = mfma_b(a[i], c2[j], acc2[i][j]);
      }
    __builtin_amdgcn_s_setprio(0);
  }

  #pragma unroll
  for (int i = 0; i < 4; ++i)
    #pragma unroll
    for (int j = 0; j < 2; ++j)
      #pragma unroll
      for (int r = 0; r < 4; ++r) {
        int mrow = m0 + wm * 64 + i * 16 + quad * 4 + r;
        if (mrow < cnt) {
          int slot = list[mrow];
          int col = n0 + wn * 32 + j * 16 + l16;
          if (MODE == 1) {
            float g = acc[i][j][r], u = acc2[i][j][r];
            float hv = g / (1.0f + __expf(-g)) * u;  // silu(g)*u
            hout[(size_t)slot * N + col] = f2bf(hv);
          } else {
            moeout[(size_t)slot * N + col] = acc[i][j][r] * gatebuf[slot];
          }
        }
      }
}

// ---------------- flash attention: split-bf16 MFMA, pre-split K/V ----------------
__global__ __launch_bounds__(256) void flash_kernel(
    const float* __restrict__ Q, const u16b* __restrict__ Kp,
    const u16b* __restrict__ Vtp, u16b* __restrict__ attnp) {
  __shared__ __attribute__((aligned(16))) u16b Khi[32 * 136];
  __shared__ __attribute__((aligned(16))) u16b Klo[32 * 136];
  __shared__ __attribute__((aligned(16))) u16b Vthi[128 * 40];
  __shared__ __attribute__((aligned(16))) u16b Vtlo[128 * 40];
  __shared__ float Ss[32 * 36];
  __shared__ __attribute__((aligned(16))) u16b Phi[32 * 40];
  __shared__ __attribute__((aligned(16))) u16b Plo[32 * 40];
  __shared__ float red[32 * 8];
  __shared__ float mrow[32], lrow[32], arow[32];

  int qt = (gridDim.x - 1) - blockIdx.x;  // big tiles first
  int h = blockIdx.y;
  int g = h >> 2;  // GQA: 4 q-heads per kv-head
  int tid = threadIdx.x;
  int wave = tid >> 6, lane = tid & 63;
  int l16 = lane & 15, quad = lane >> 4;
  int sm = wave >> 1, sn = wave & 1;

  s8v qhi[4], qlo[4];
  {
    const float* qp = Q + (size_t)(qt * 32 + sm * 16 + l16) * 2048 + h * 128 + quad * 8;
    #pragma unroll
    for (int kc = 0; kc < 4; ++kc) {
      float4 f0 = *(const float4*)(qp + kc * 32);
      float4 f1 = *(const float4*)(qp + kc * 32 + 4);
      float f[8] = {f0.x, f0.y, f0.z, f0.w, f1.x, f1.y, f1.z, f1.w};
      u16b hi[8], lo[8];
      #pragma unroll
      for (int x = 0; x < 8; ++x) split2(f[x], hi[x], lo[x]);
      FragCvt ch, cl;
      ch.q[0] = pack4(hi); ch.q[1] = pack4(hi + 4);
      cl.q[0] = pack4(lo); cl.q[1] = pack4(lo + 4);
      qhi[kc] = ch.v; qlo[kc] = cl.v;
    }
  }

  if (tid < 32) { mrow[tid] = -1e30f; lrow[tid] = 0.f; }

  f4v o[4];
  #pragma unroll
  for (int db = 0; db < 4; ++db) o[db] = (f4v)0.0f;

  int krow = tid >> 3, ksk = (tid & 7) * 16;  // K staging: 8 thr/row x 16 d
  int vd = tid >> 1, vk0 = (tid & 1) * 16;    // V staging: 2 thr/row x 16 kv
  int sr = tid >> 3, sp = tid & 7;            // softmax mapping

  const u16b* krow_h = &Khi[(sn * 16 + l16) * 136];
  const u16b* krow_l = &Klo[(sn * 16 + l16) * 136];

  for (int kt = 0; kt <= qt; ++kt) {
    // ---- issue staging loads (pure copies; overlap with prev tile tail) ----
    const u16b* ksh = Kp + (size_t)(kt * 32 + krow) * 1024 + g * 128 + ksk;
    s8v kh0 = *(const s8v*)(ksh);
    s8v kh1 = *(const s8v*)(ksh + 8);
    s8v kl0 = *(const s8v*)(ksh + 512);
    s8v kl1 = *(const s8v*)(ksh + 520);
    const u16b* vsh = Vtp + (size_t)(g * 128 + vd) * 4096 + kt * 32 + vk0;
    s8v vh0 = *(const s8v*)(vsh);
    s8v vh1 = *(const s8v*)(vsh + 8);
    s8v vl0 = *(const s8v*)(vsh + 2048);
    s8v vl1 = *(const s8v*)(vsh + 2056);
    __syncthreads();
    {
      int kb = krow * 136 + ksk;
      *(s8v*)&Khi[kb]     = kh0;
      *(s8v*)&Khi[kb + 8] = kh1;
      *(s8v*)&Klo[kb]     = kl0;
      *(s8v*)&Klo[kb + 8] = kl1;
      int vb = vd * 40 + vk0;
      *(s8v*)&Vthi[vb]     = vh0;
      *(s8v*)&Vthi[vb + 8] = vh1;
      *(s8v*)&Vtlo[vb]     = vl0;
      *(s8v*)&Vtlo[vb + 8] = vl1;
    }
    __syncthreads();
    // ---- S = Q K^T via MFMA (3-term split) ----
    f4v a0 = (f4v)0.0f, a1 = (f4v)0.0f, a2 = (f4v)0.0f;
    __builtin_amdgcn_s_setprio(1);
    #pragma unroll
    for (int kc = 0; kc < 4; ++kc) {
      s8v kh = *(const s8v*)(krow_h + kc * 32 + quad * 8);
      s8v kl = *(const s8v*)(krow_l + kc * 32 + quad * 8);
      a0 = mfma_b(qhi[kc], kh, a0);
      a1 = mfma_b(qhi[kc], kl, a1);
      a2 = mfma_b(qlo[kc], kh, a2);
    }
    __builtin_amdgcn_s_setprio(0);
    {
      f4v sacc = a0 + a1 + a2;
      const float sc = 0.08838834764831845f;  // 1/sqrt(128)
      #pragma unroll
      for (int r = 0; r < 4; ++r) {
        int row_l = sm * 16 + quad * 4 + r;
        int col_l = sn * 16 + l16;
        int qb = qt * 32 + row_l, kb2 = kt * 32 + col_l;
        Ss[row_l * 36 + col_l] = (kb2 <= qb) ? sacc[r] * sc : -1e30f;
      }
    }
    __syncthreads();
    // ---- online softmax ----
    float mx = -3e38f;
    #pragma unroll
    for (int c = sp * 4; c < sp * 4 + 4; ++c) mx = fmaxf(mx, Ss[sr * 36 + c]);
    red[sr * 8 + sp] = mx;
    __syncthreads();
    if (sp == 0) {
      float mn = mrow[sr];
      #pragma unroll
      for (int p = 0; p < 8; ++p) mn = fmaxf(mn, red[sr * 8 + p]);
      arow[sr] = __expf(mrow[sr] - mn);
      mrow[sr] = mn;
    }
    __syncthreads();
    {
      float m = mrow[sr];
      float sum = 0.f;
      #pragma unroll
      for (int c = sp * 4; c < sp * 4 + 4; ++c) {
        float e2 = __expf(Ss[sr * 36 + c] - m);
        u16b eh, el;
        split2(e2, eh, el);
        Phi[sr * 40 + c] = eh;
        Plo[sr * 40 + c] = el;
        sum += e2;
      }
      red[sr * 8 + sp] = sum;
    }
    __syncthreads();
    if (sp == 0) {
      float s2 = 0.f;
      #pragma unroll
      for (int p = 0; p < 8; ++p) s2 += red[sr * 8 + p];
      lrow[sr] = lrow[sr] * arow[sr] + s2;
    }
    // ---- PV via MFMA ----
    {
      f4v arv;
      arv[0] = arow[sm * 16 + quad * 4 + 0];
      arv[1] = arow[sm * 16 + quad * 4 + 1];
      arv[2] = arow[sm * 16 + quad * 4 + 2];
      arv[3] = arow[sm * 16 + quad * 4 + 3];
      #pragma unroll
      for (int db = 0; db < 4; ++db) o[db] *= arv;

      s8v pah = *(const s8v*)&Phi[(sm * 16 + l16) * 40 + quad * 8];
      s8v pal = *(const s8v*)&Plo[(sm * 16 + l16) * 40 + quad * 8];
      __builtin_amdgcn_s_setprio(1);
      #pragma unroll
      for (int db = 0; db < 4; ++db) {
        int vrow = sn * 64 + db * 16 + l16;
        s8v vh = *(const s8v*)&Vthi[vrow * 40 + quad * 8];
        s8v vl = *(const s8v*)&Vtlo[vrow * 40 + quad * 8];
        o[db] = mfma_b(pah, vh, o[db]);
        o[db] = mfma_b(pah, vl, o[db]);
        o[db] = mfma_b(pal, vh, o[db]);
      }
      __builtin_amdgcn_s_setprio(0);
    }
  }
  __syncthreads();
  {
    int row0 = sm * 16 + quad * 4;
    f4v invv;
    invv[0] = 1.f / lrow[row0 + 0];
    invv[1] = 1.f / lrow[row0 + 1];
    invv[2] = 1.f / lrow[row0 + 2];
    invv[3] = 1.f / lrow[row0 + 3];
    #pragma unroll
    for (int db = 0; db < 4; ++db) o[db] *= invv;
    #pragma unroll
    for (int r = 0; r < 4; ++r) {
      u16b* ob = attnp + (size_t)(qt * 32 + row0 + r) * 4096 + h * 128 + sn * 64 + l16;
      #pragma unroll
      for (int db = 0; db < 4; ++db) {
        u16b hh, ll;
        split2(o[db][r], hh, ll);
        ob[db * 16] = hh;
        ob[2048 + db * 16] = ll;
      }
    }
  }
}

// ---------------- router ----------------
__global__ __launch_bounds__(256) void router_kernel(
    const float* __restrict__ xn2, const float* __restrict__ rw,
    int* __restrict__ counts, int* __restrict__ list, float* __restrict__ gatebuf) {
  __shared__ float red[256];
  __shared__ float logits[16];
  int t = blockIdx.x, tid = threadIdx.x;
  int e = tid >> 4, p = tid & 15;
  const float* xr = xn2 + (size_t)t * HID;
  float s = 0.f;
  for (int j = p * 128; j < p * 128 + 128; ++j) s += xr[j] * rw[j * 16 + e];
  red[tid] = s;
  __syncthreads();
  if (tid < 16) {
    float l = 0.f;
    #pragma unroll
    for (int p2 = 0; p2 < 16; ++p2) l += red[tid * 16 + p2];
    logits[tid] = l;
  }
  __syncthreads();
  if (tid == 0) {
    int i0 = 0; float l0 = logits[0];
    for (int i = 1; i < 16; ++i) if (logits[i] > l0) { l0 = logits[i]; i0 = i; }
    int i1 = -1; float l1 = -3e38f;
    for (int i = 0; i < 16; ++i) if (i != i0 && logits[i] > l1) { l1 = logits[i]; i1 = i; }
    float g0 = 1.f / (1.f + __expf(l1 - l0));
    float g1 = 1.f - g0;
    int s0 = atomicAdd(&counts[i0], 1);
    list[i0 * T_TOK + s0] = t * 2;
    gatebuf[t * 2] = g0;
    int s1 = atomicAdd(&counts[i1], 1);
    list[i1 * T_TOK + s1] = t * 2 + 1;
    gatebuf[t * 2 + 1] = g1;
  }
}

// ---------------- final ----------------
__global__ __launch_bounds__(256) void final_kernel(
    const float* __restrict__ moeout, const float* __restrict__ resid,
    const float* __restrict__ W, float* __restrict__ out) {
  __shared__ float lds[4];
  int t = blockIdx.x, tid = threadIdx.x;
  const float* m0 = moeout + (size_t)(2 * t) * HID;
  const float* m1 = moeout + (size_t)(2 * t + 1) * HID;
  const float* rr = resid + (size_t)t * HID;
  float v[8]; float ss = 0.f;
  #pragma unroll
  for (int i = 0; i < 8; ++i) {
    int j = tid + i * 256;
    v[i] = m0[j] + m1[j] + rr[j];
    ss += v[i] * v[i];
  }
  float tot = blk_sum_256(ss, lds);
  float scale = rsqrtf(tot * (1.f / (float)HID) + 1e-6f);
  float* orow = out + (size_t)t * HID;
  #pragma unroll
  for (int i = 0; i < 8; ++i) {
    int j = tid + i * 256;
    orow[j] = v[i] * scale * (1.f + W[j]);
  }
}

extern "C" void kernel_launch(void* const* d_in, const int* in_sizes, int n_in,
                              void* d_out, int out_size, void* d_ws, size_t ws_size,
                              hipStream_t stream) {
  const int* input_ids   = (const int*)d_in[0];
  const int* positions   = (const int*)d_in[1];
  const float* hidden    = (const float*)d_in[2];
  const float* embed_w   = (const float*)d_in[4];
  const float* fc_w      = (const float*)d_in[5];
  const float* pre_emb   = (const float*)d_in[6];
  const float* pre_hid   = (const float*)d_in[7];
  const float* in_ln     = (const float*)d_in[8];
  const float* post_ln   = (const float*)d_in[9];
  const float* final_w   = (const float*)d_in[10];
  const float* wq        = (const float*)d_in[11];
  const float* wk        = (const float*)d_in[12];
  const float* wv        = (const float*)d_in[13];
  const float* wo        = (const float*)d_in[14];
  const float* qnw       = (const float*)d_in[15];
  const float* knw       = (const float*)d_in[16];
  const float* rw        = (const float*)d_in[17];
  const float* wg        = (const float*)d_in[18];
  const float* wu        = (const float*)d_in[19];
  const float* wd        = (const float*)d_in[20];

  char* ws = (char*)d_ws;
  u16b*  catp   = (u16b*)(ws + 0);            // 2048 x 8192 bf16 = 32 MB
  u16b*  qkvw   = (u16b*)(ws + 0);            // 3072 x 4096 bf16 = 24 MB
  float* moeout = (float*)(ws + 0);           // 4096 x 2048 f32 = 32 MB
  u16b*  vtp    = (u16b*)(ws + 25165824);     // 512 x 4096 bf16 = 4 MB (gap after qkvw)
  float* x      = (float*)(ws + 33554432);    // 16 MB fc out / residual1
  u16b*  xnp    = (u16b*)(ws + 50331648);     // 2048 x 4096 bf16 = 16 MB
  u16b*  wotw   = (u16b*)(ws + 50331648);     // 2048 x 4096 bf16 = 16 MB (overlays xnp)
  float* q      = (float*)(ws + 67108864);    // 16 MB
  u16b*  hbuf16 = (u16b*)(ws + 67108864);     // 4096 x 1024 bf16 = 8 MB (q dead)
  float* kbuf   = (float*)(ws + 83886080);    // 4 MB (raw k proj, f32)
  u16b*  kp     = (u16b*)(ws + 88080384);     // 2048 x 1024 bf16 = 4 MB (split K)
  u16b*  fctw   = (u16b*)(ws + 92274688);     // 2048 x 8192 bf16 = 32 MB
  u16b*  attnp  = (u16b*)(ws + 92274688);     // 2048 x 4096 bf16 = 16 MB
  float* x2     = (float*)(ws + 109051904);   // 16 MB residual2
  float* xn2    = (float*)(ws + 125829120);   // 16 MB
  int*   counts = (int*)(ws + 142606336);     // 64 B
  int*   list   = (int*)(ws + 142606592);     // 128 KB
  float* gateb  = (float*)(ws + 142737664);   // 16 KB

  zero_counts_kernel<<<1, 64, 0, stream>>>(counts);
  embed_cat_kernel<<<dim3(2048, 2), 256, 0, stream>>>(input_ids, embed_w, hidden,
                                                      pre_emb, pre_hid, catp);
  tsplit_kernel<<<dim3(32, 64), 256, 0, stream>>>(fc_w, fctw, 4096, 2048, 0);
  gemm_bs<0><<<dim3(32, 16), 256, 0, stream>>>(catp, fctw, x, nullptr,
                                               nullptr, nullptr, 2048, 2048, 4096);
  tsplit_kernel<<<dim3(32, 32), 256, 0, stream>>>(wq, qkvw, 2048, 2048, 0);
  tsplit_kernel<<<dim3(8, 32), 256, 0, stream>>>(wk, qkvw, 2048, 512, 2048);
  tsplit_kernel<<<dim3(8, 32), 256, 0, stream>>>(wv, qkvw, 2048, 512, 2560);
  rms_split_kernel<<<2048, 256, 0, stream>>>(x, in_ln, xnp);
  gemm_bs<1><<<dim3(48, 16), 256, 0, stream>>>(xnp, qkvw, q, nullptr,
                                               kbuf, vtp, 2048, 3072, 2048);
  tsplit_kernel<<<dim3(32, 32), 256, 0, stream>>>(wo, wotw, 2048, 2048, 0);
  qknorm_rope_kernel<<<dim3(2048, 16), 128, 0, stream>>>(q, qnw, positions, 2048);
  knorm_rope_split_kernel<<<dim3(2048, 4), 128, 0, stream>>>(kbuf, knw, positions, kp);
  flash_kernel<<<dim3(64, 16), 256, 0, stream>>>(q, kp, vtp, attnp);
  gemm_bs<0><<<dim3(32, 16), 256, 0, stream>>>(attnp, wotw, x2, x,
                                               nullptr, nullptr, 2048, 2048, 2048);
  rms_f32_kernel<<<2048, 256, 0, stream>>>(x2, post_ln, xn2);
  rms_split_kernel<<<2048, 256, 0, stream>>>(x2, post_ln, xnp);
  router_kernel<<<2048, 256, 0, stream>>>(xn2, rw, counts, list, gateb);
  gemm_moe<1><<<dim3(16, 16, 16), 256, 0, stream>>>(xnp, 4096, wg, wu, hbuf16,
                                                    nullptr, counts, list, nullptr,
                                                    1024, 2048);
  gemm_moe<2><<<dim3(32, 16, 16), 256, 0, stream>>>(hbuf16, 1024, wd, nullptr, nullptr,
                                                    moeout, counts, list, gateb,
                                                    2048, 1024);
  final_kernel<<<2048, 256, 0, stream>>>(moeout, x2, final_w, (float*)d_out);
}